// Round 5
// baseline (12017.921 us; speedup 1.0000x reference)
//
#include <hip/hip_runtime.h>
#include <hip/hip_bf16.h>
#include <cstdint>
#include <cstddef>

// Problem constants: L=256, B=16, I=2048, H=2048, S=R=T=32
#define L_DIM 256
#define B_DIM 16
#define I_DIM 2048
#define H_DIM 2048
#define G4    8192
#define MROWS 4096
#define NWG   256

typedef __hip_bfloat16 bf16;
typedef __bf16 bf16x8_t __attribute__((ext_vector_type(8)));
typedef float f32x4_t   __attribute__((ext_vector_type(4)));

__device__ __forceinline__ bf16 f2b(float f) { return __float2bfloat16(f); }

__device__ __forceinline__ void gl_lds16(const void* g, void* l) {
  __builtin_amdgcn_global_load_lds(
      (const __attribute__((address_space(1))) unsigned int*)g,
      (__attribute__((address_space(3))) unsigned int*)l, 16, 0, 0);
}

__device__ __forceinline__ float sigmoidf_(float x) { return 1.f / (1.f + expf(-x)); }

// ---------------------------------------------------------------------------
// K0: prep — hi/lo split casts, padded Ww, h0 into Xh slot 0
// ---------------------------------------------------------------------------
__global__ void prep_kernel(const float* __restrict__ Wih, const float* __restrict__ Whh,
                            const float* __restrict__ inp, const float* __restrict__ Www,
                            const float* __restrict__ Wwb, const float* __restrict__ Wrw,
                            const float* __restrict__ h0,
                            bf16* __restrict__ Wih_hi, bf16* __restrict__ Wih_lo,
                            bf16* __restrict__ Whh_hi, bf16* __restrict__ Whh_lo,
                            bf16* __restrict__ inp_hi, bf16* __restrict__ inp_lo,
                            bf16* __restrict__ Wq_hi, bf16* __restrict__ Wq_lo,
                            bf16* __restrict__ Wr_hi, bf16* __restrict__ Wr_lo,
                            float* __restrict__ wbpad,
                            bf16* __restrict__ XhHi, bf16* __restrict__ XhLo)
{
  size_t idx0 = (size_t)blockIdx.x * blockDim.x + threadIdx.x;
  size_t stride = (size_t)gridDim.x * blockDim.x;
  for (size_t i = idx0; i < 16777216ull; i += stride) {
    float a = Wih[i];
    bf16 ah = f2b(a);
    Wih_hi[i] = ah;
    Wih_lo[i] = f2b(a - (float)ah);
    float b = Whh[i];
    bf16 bh = f2b(b);
    Whh_hi[i] = bh;
    Whh_lo[i] = f2b(b - (float)bh);
  }
  for (size_t i = idx0; i < 8388608ull; i += stride) {
    float a = inp[i];
    bf16 ah = f2b(a);
    inp_hi[i] = ah;
    inp_lo[i] = f2b(a - (float)ah);
  }
  for (size_t i = idx0; i < 262144ull; i += stride) {
    size_t r = i >> 11;
    float q = (r < 97) ? Www[i] : 0.f;
    bf16 qh = f2b(q);
    Wq_hi[i] = qh;
    Wq_lo[i] = f2b(q - (float)qh);
    float rr = Wrw[i];
    bf16 rh = f2b(rr);
    Wr_hi[i] = rh;
    Wr_lo[i] = f2b(rr - (float)rh);
  }
  for (size_t i = idx0; i < 128ull; i += stride) wbpad[i] = (i < 97) ? Wwb[i] : 0.f;
  for (size_t i = idx0; i < 32768ull; i += stride) {
    float h = h0[i];
    bf16 hh = f2b(h);
    XhHi[i] = hh;                       // Xh slot 0 = h0
    XhLo[i] = f2b(h - (float)hh);
  }
}

// ---------------------------------------------------------------------------
// K1: persistent LSTM. 256 WGs x 1024 thr (cooperative launch, 1 WG/CU).
// WG owns 8 hidden units (32 gate rows); wave wv owns K-slice [128*wv,+128).
// W_ih and W_hh hi/lo fragments register-resident (loaded once).
// Per step: 48 MFMAs/wave; LDS reduce; gates on 128 thr (c in registers);
// h hi/lo -> Xh slot t+1; grid barrier (atomic counter, monotonic target).
// ---------------------------------------------------------------------------
__global__ __launch_bounds__(1024, 4) void lstm_persist(
    const bf16* __restrict__ Whh_hi, const bf16* __restrict__ Whh_lo,
    const bf16* __restrict__ Wih_hi, const bf16* __restrict__ Wih_lo,
    const bf16* __restrict__ inp_hi, const bf16* __restrict__ inp_lo,
    const float* __restrict__ bih, const float* __restrict__ bhh,
    const float* __restrict__ c0,
    bf16* __restrict__ XhHi, bf16* __restrict__ XhLo,
    int* bar)
{
  const int tid  = threadIdx.x;
  const int lane = tid & 63;
  const int wv   = tid >> 6;          // 0..15
  const int wg   = blockIdx.x;        // 0..255
  const int j0   = wg * 8;
  const int kw   = wv * 128;

  __shared__ float part[16][2][16][17];
  __shared__ float gs[32][16];

  // ---- register-resident weight fragments (B-operand layout) ----
  bf16x8_t whh_h[2][4], whh_l[2][4], wih_h[2][4], wih_l[2][4];
  {
    const int nn  = lane & 15;
    const int kfo = (lane >> 4) * 8;
#pragma unroll
    for (int nt = 0; nt < 2; ++nt) {
      const int n = nt * 16 + nn;
      const int gate = n >> 3, jj = n & 7;
      const size_t grow = (size_t)(gate * H_DIM + j0 + jj) * 2048;
#pragma unroll
      for (int ks = 0; ks < 4; ++ks) {
        const size_t o = grow + kw + ks * 32 + kfo;
        whh_h[nt][ks] = *reinterpret_cast<const bf16x8_t*>(Whh_hi + o);
        whh_l[nt][ks] = *reinterpret_cast<const bf16x8_t*>(Whh_lo + o);
        wih_h[nt][ks] = *reinterpret_cast<const bf16x8_t*>(Wih_hi + o);
        wih_l[nt][ks] = *reinterpret_cast<const bf16x8_t*>(Wih_lo + o);
      }
    }
  }

  // ---- per-thread cell state + bias (threads 0..127) ----
  float c_reg = 0.f, cbr0 = 0.f, cbr1 = 0.f, cbr2 = 0.f, cbr3 = 0.f;
  if (tid < 128) {
    const int bb = tid & 15, jj = tid >> 4;
    const int j = j0 + jj;
    c_reg = c0[bb * H_DIM + j];
    cbr0 = bih[0 * H_DIM + j] + bhh[0 * H_DIM + j];
    cbr1 = bih[1 * H_DIM + j] + bhh[1 * H_DIM + j];
    cbr2 = bih[2 * H_DIM + j] + bhh[2 * H_DIM + j];
    cbr3 = bih[3 * H_DIM + j] + bhh[3 * H_DIM + j];
  }

  const size_t arow = (size_t)(lane & 15) * 2048 + kw + (lane >> 4) * 8;

  // prefetch x frags for t=0
  bf16x8_t xh[4], xl[4];
#pragma unroll
  for (int ks = 0; ks < 4; ++ks) {
    xh[ks] = *reinterpret_cast<const bf16x8_t*>(inp_hi + arow + ks * 32);
    xl[ks] = *reinterpret_cast<const bf16x8_t*>(inp_lo + arow + ks * 32);
  }

  for (int t = 0; t < L_DIM; ++t) {
    // h frags from Xh slot t
    const size_t hoff = (size_t)t * 16 * 2048 + arow;
    bf16x8_t hh[4], hl[4];
#pragma unroll
    for (int ks = 0; ks < 4; ++ks) {
      hh[ks] = *reinterpret_cast<const bf16x8_t*>(XhHi + hoff + ks * 32);
      hl[ks] = *reinterpret_cast<const bf16x8_t*>(XhLo + hoff + ks * 32);
    }

    f32x4_t acc0 = {0.f, 0.f, 0.f, 0.f}, acc1 = {0.f, 0.f, 0.f, 0.f};
#pragma unroll
    for (int ks = 0; ks < 4; ++ks) {
      acc0 = __builtin_amdgcn_mfma_f32_16x16x32_bf16(xh[ks], wih_h[0][ks], acc0, 0, 0, 0);
      acc0 = __builtin_amdgcn_mfma_f32_16x16x32_bf16(xh[ks], wih_l[0][ks], acc0, 0, 0, 0);
      acc0 = __builtin_amdgcn_mfma_f32_16x16x32_bf16(xl[ks], wih_h[0][ks], acc0, 0, 0, 0);
      acc0 = __builtin_amdgcn_mfma_f32_16x16x32_bf16(hh[ks], whh_h[0][ks], acc0, 0, 0, 0);
      acc0 = __builtin_amdgcn_mfma_f32_16x16x32_bf16(hh[ks], whh_l[0][ks], acc0, 0, 0, 0);
      acc0 = __builtin_amdgcn_mfma_f32_16x16x32_bf16(hl[ks], whh_h[0][ks], acc0, 0, 0, 0);
      acc1 = __builtin_amdgcn_mfma_f32_16x16x32_bf16(xh[ks], wih_h[1][ks], acc1, 0, 0, 0);
      acc1 = __builtin_amdgcn_mfma_f32_16x16x32_bf16(xh[ks], wih_l[1][ks], acc1, 0, 0, 0);
      acc1 = __builtin_amdgcn_mfma_f32_16x16x32_bf16(xl[ks], wih_h[1][ks], acc1, 0, 0, 0);
      acc1 = __builtin_amdgcn_mfma_f32_16x16x32_bf16(hh[ks], whh_h[1][ks], acc1, 0, 0, 0);
      acc1 = __builtin_amdgcn_mfma_f32_16x16x32_bf16(hh[ks], whh_l[1][ks], acc1, 0, 0, 0);
      acc1 = __builtin_amdgcn_mfma_f32_16x16x32_bf16(hl[ks], whh_h[1][ks], acc1, 0, 0, 0);
    }
#pragma unroll
    for (int r = 0; r < 4; ++r) {
      part[wv][0][(lane >> 4) * 4 + r][lane & 15] = acc0[r];
      part[wv][1][(lane >> 4) * 4 + r][lane & 15] = acc1[r];
    }
    __syncthreads();

    if (tid < 512) {
      const int bb = tid & 15, n = tid >> 4;
      const int nt = n >> 4, nn = n & 15;
      float s = 0.f;
#pragma unroll
      for (int v = 0; v < 16; ++v) s += part[v][nt][bb][nn];
      gs[n][bb] = s;
    }
    __syncthreads();

    if (tid < 128) {
      const int bb = tid & 15, jj = tid >> 4;
      const float gi = gs[0 * 8 + jj][bb] + cbr0;
      const float gf = gs[1 * 8 + jj][bb] + cbr1;
      const float gg = gs[2 * 8 + jj][bb] + cbr2;
      const float go = gs[3 * 8 + jj][bb] + cbr3;
      const float i_ = sigmoidf_(gi);
      const float f_ = sigmoidf_(gf);
      const float g_ = tanhf(gg);
      const float o_ = sigmoidf_(go);
      c_reg = f_ * c_reg + i_ * g_;
      const float h = o_ * tanhf(c_reg);
      const bf16 hhv = f2b(h);
      const bf16 hlv = f2b(h - (float)hhv);
      const size_t oidx = (size_t)(t + 1) * 16 * 2048 + (size_t)bb * 2048 + j0 + jj;
      XhHi[oidx] = hhv;
      XhLo[oidx] = hlv;
    }
    __syncthreads();   // all waves' stores drained (vmcnt0) before arrive; LDS reuse fence

    // prefetch x frags for t+1 (independent of barrier)
    const int tp = (t < L_DIM - 1) ? (t + 1) : (L_DIM - 1);
    const size_t xoff = (size_t)tp * 16 * 2048 + arow;
#pragma unroll
    for (int ks = 0; ks < 4; ++ks) {
      xh[ks] = *reinterpret_cast<const bf16x8_t*>(inp_hi + xoff + ks * 32);
      xl[ks] = *reinterpret_cast<const bf16x8_t*>(inp_lo + xoff + ks * 32);
    }

    if (t < L_DIM - 1) {
      if (tid == 0) {
        __threadfence();   // release: h stores visible device-wide
        __hip_atomic_fetch_add(bar, 1, __ATOMIC_ACQ_REL, __HIP_MEMORY_SCOPE_AGENT);
        const int target = (t + 1) * NWG;
        while (__hip_atomic_load(bar, __ATOMIC_RELAXED, __HIP_MEMORY_SCOPE_AGENT) < target)
          __builtin_amdgcn_s_sleep(2);
        __threadfence();   // acquire: invalidate stale L1/L2 before h reads
      }
      __syncthreads();
    }
  }
}

// ---------------------------------------------------------------------------
// K2: split-bf16 (hi+lo) NT GEMM — ~fp32 via 3 products (phase C only now).
// MODE 1: C = acc + bias ; MODE 2: C = tanh(acc + bias)
// ---------------------------------------------------------------------------
template <int MODE>
__global__ __launch_bounds__(256) void gemm_nt3(const bf16* __restrict__ A_hi,
                                                const bf16* __restrict__ A_lo,
                                                const bf16* __restrict__ B_hi,
                                                const bf16* __restrict__ B_lo,
                                                const float* __restrict__ bias,
                                                float* __restrict__ C,
                                                int M, int N, int K)
{
  __shared__ __align__(16) bf16 As[2][128 * 32];
  __shared__ __align__(16) bf16 Bs[2][128 * 32];
  const int tid  = threadIdx.x;
  const int lane = tid & 63;
  const int w    = tid >> 6;
  const int wm   = w >> 1, wn = w & 1;
  const int m0   = blockIdx.x * 128, n0 = blockIdx.y * 128;

  f32x4_t acc[4][4];
#pragma unroll
  for (int m = 0; m < 4; ++m)
#pragma unroll
    for (int n = 0; n < 4; ++n) acc[m][n] = (f32x4_t){0.f, 0.f, 0.f, 0.f};

  for (int k0 = 0; k0 < K; k0 += 32) {
#pragma unroll
    for (int r = 0; r < 2; ++r) {
      const int base = w * 2048 + r * 1024;
      const int off  = base + lane * 16;
      const int e    = off >> 1;
      const int row  = e >> 5;
      const int col  = e & 31;
      const size_t gA = (size_t)(m0 + row) * K + (k0 + col);
      const size_t gB = (size_t)(n0 + row) * K + (k0 + col);
      gl_lds16(A_hi + gA, (char*)As[0] + base);
      gl_lds16(A_lo + gA, (char*)As[1] + base);
      gl_lds16(B_hi + gB, (char*)Bs[0] + base);
      gl_lds16(B_lo + gB, (char*)Bs[1] + base);
    }
    __syncthreads();

    bf16x8_t afh[4], afl[4], bfh[4], bfl[4];
    const int kb = (lane >> 4) * 16;
#pragma unroll
    for (int m = 0; m < 4; ++m) {
      const int ro = (wm * 64 + m * 16 + (lane & 15)) * 64 + kb;
      afh[m] = *reinterpret_cast<const bf16x8_t*>((const char*)As[0] + ro);
      afl[m] = *reinterpret_cast<const bf16x8_t*>((const char*)As[1] + ro);
    }
#pragma unroll
    for (int n = 0; n < 4; ++n) {
      const int ro = (wn * 64 + n * 16 + (lane & 15)) * 64 + kb;
      bfh[n] = *reinterpret_cast<const bf16x8_t*>((const char*)Bs[0] + ro);
      bfl[n] = *reinterpret_cast<const bf16x8_t*>((const char*)Bs[1] + ro);
    }
#pragma unroll
    for (int m = 0; m < 4; ++m)
#pragma unroll
      for (int n = 0; n < 4; ++n) {
        acc[m][n] = __builtin_amdgcn_mfma_f32_16x16x32_bf16(afh[m], bfh[n], acc[m][n], 0, 0, 0);
        acc[m][n] = __builtin_amdgcn_mfma_f32_16x16x32_bf16(afh[m], bfl[n], acc[m][n], 0, 0, 0);
        acc[m][n] = __builtin_amdgcn_mfma_f32_16x16x32_bf16(afl[m], bfh[n], acc[m][n], 0, 0, 0);
      }
    __syncthreads();
  }

#pragma unroll
  for (int m = 0; m < 4; ++m) {
#pragma unroll
    for (int n = 0; n < 4; ++n) {
      const int col = n0 + wn * 64 + n * 16 + (lane & 15);
      const float bv = bias[col];
#pragma unroll
      for (int r = 0; r < 4; ++r) {
        const int row = m0 + wm * 64 + m * 16 + (lane >> 4) * 4 + r;
        float v = acc[m][n][r] + bv;
        if (MODE == 2) v = tanhf(v);
        C[(size_t)row * N + col] = v;
      }
    }
  }
}

// ---------------------------------------------------------------------------
// K3: FWM scan. 16 WGs (one per batch) x 1024 thr. Fm register-resident.
// ---------------------------------------------------------------------------
__global__ __launch_bounds__(1024) void fwm_scan(const float* __restrict__ Wall,   // (4096,128)
                                                 const float* __restrict__ RVall,  // (4096,128)
                                                 const float* __restrict__ F0,     // (16,1024,32)
                                                 float* __restrict__ QS)           // (4096,32)
{
  const int b    = blockIdx.x;
  const int tid  = threadIdx.x;
  const int lane = tid & 63;
  const int wv   = tid >> 6;

  __shared__ float s_s[32], s_r[32], s_tv[32], s_bb;
  __shared__ float s_rv[128];
  __shared__ float s_v[32], s_u[32], s_q[32];
  __shared__ float s_red[16];
  __shared__ float s_inv;

  float F[16][2];
#pragma unroll
  for (int i = 0; i < 16; ++i)
#pragma unroll
    for (int j = 0; j < 2; ++j)
      F[i][j] = F0[((size_t)b * 1024 + (16 * lane + i)) * 32 + 2 * wv + j];

  const int si    = lane >> 1;
  const int rbase = 16 * (lane & 1);

  for (int t = 0; t < 256; ++t) {
    const float* wrow  = Wall  + (size_t)(t * 16 + b) * 128;
    const float* rvrow = RVall + (size_t)(t * 16 + b) * 128;
    __syncthreads();
    if (tid < 32)            s_s[tid]        = tanhf(wrow[tid]);
    else if (tid < 64)       s_r[tid - 32]   = tanhf(wrow[tid]);
    else if (tid < 96)       s_tv[tid - 64]  = tanhf(wrow[tid]);
    else if (tid == 96)      s_bb            = sigmoidf_(wrow[96] + 1.f);
    else if (tid >= 128 && tid < 256) s_rv[tid - 128] = rvrow[tid - 128];
    __syncthreads();

    const float sv = s_s[si];
    float sr[16];
#pragma unroll
    for (int i = 0; i < 16; ++i) sr[i] = sv * s_r[rbase + i];

    float p0 = 0.f, p1 = 0.f;
#pragma unroll
    for (int i = 0; i < 16; ++i) { p0 += sr[i] * F[i][0]; p1 += sr[i] * F[i][1]; }
#pragma unroll
    for (int m = 1; m < 64; m <<= 1) { p0 += __shfl_xor(p0, m); p1 += __shfl_xor(p1, m); }
    if (lane == 0) { s_v[2 * wv] = p0; s_v[2 * wv + 1] = p1; }
    __syncthreads();

    if (tid < 32) s_u[tid] = s_bb * (s_tv[tid] - s_v[tid]);
    __syncthreads();

    const float u0 = s_u[2 * wv], u1 = s_u[2 * wv + 1];
    float nn = 0.f;
#pragma unroll
    for (int i = 0; i < 16; ++i) {
      F[i][0] += sr[i] * u0;
      F[i][1] += sr[i] * u1;
      nn += F[i][0] * F[i][0] + F[i][1] * F[i][1];
    }
#pragma unroll
    for (int m = 1; m < 64; m <<= 1) nn += __shfl_xor(nn, m);
    if (lane == 0) s_red[wv] = nn;
    __syncthreads();
    if (tid == 0) {
      float tot = 0.f;
#pragma unroll
      for (int k = 0; k < 16; ++k) tot += s_red[k];
      const float n_ = sqrtf(tot);
      const float d  = fmaxf(n_ - 1.f, 0.f) + 1.f;
      s_inv = 1.f / d;
    }
    __syncthreads();
    const float inv = s_inv;
#pragma unroll
    for (int i = 0; i < 16; ++i) { F[i][0] *= inv; F[i][1] *= inv; }

#pragma unroll 1
    for (int jit = 0; jit < 3; ++jit) {
      const float qv = (jit == 0) ? s_rv[si] : s_q[si];
      float c0 = 0.f, c1 = 0.f;
#pragma unroll
      for (int i = 0; i < 16; ++i) {
        const float cf = qv * s_rv[32 + 32 * jit + rbase + i];
        c0 += cf * F[i][0];
        c1 += cf * F[i][1];
      }
#pragma unroll
      for (int m = 1; m < 64; m <<= 1) { c0 += __shfl_xor(c0, m); c1 += __shfl_xor(c1, m); }
      if (lane == 0) { s_v[2 * wv] = c0; s_v[2 * wv + 1] = c1; }
      __syncthreads();
      if (wv == 0 && lane < 32) {
        const float x = s_v[lane];
        float mval = x;
#pragma unroll
        for (int m = 1; m < 32; m <<= 1) mval += __shfl_xor(mval, m);
        mval *= (1.f / 32.f);
        const float dl = x - mval;
        float var = dl * dl;
#pragma unroll
        for (int m = 1; m < 32; m <<= 1) var += __shfl_xor(var, m);
        var *= (1.f / 32.f);
        s_q[lane] = dl * rsqrtf(var + 1e-5f);
      }
      __syncthreads();
    }
    if (wv == 0 && lane < 32) QS[(size_t)(t * 16 + b) * 32 + lane] = s_q[lane];
  }
}

// ---------------------------------------------------------------------------
// K4: out = (XhHi+XhLo) + QS @ Wlin^T + blin
// ---------------------------------------------------------------------------
__global__ __launch_bounds__(256) void out_kernel(const bf16* __restrict__ Xh1Hi,
                                                  const bf16* __restrict__ Xh1Lo,
                                                  const float* __restrict__ QS,
                                                  const float* __restrict__ Wlin,  // (2048,32)
                                                  const float* __restrict__ blin,
                                                  float* __restrict__ out)
{
  __shared__ float qs[32];
  const int row = blockIdx.x;
  if (threadIdx.x < 32) qs[threadIdx.x] = QS[(size_t)row * 32 + threadIdx.x];
  __syncthreads();
  for (int h = threadIdx.x; h < H_DIM; h += 256) {
    const size_t xi = (size_t)row * H_DIM + h;
    float acc = (float)Xh1Hi[xi] + (float)Xh1Lo[xi] + blin[h];
    const float* wr = Wlin + (size_t)h * 32;
#pragma unroll
    for (int t2 = 0; t2 < 32; ++t2) acc += qs[t2] * wr[t2];
    out[xi] = acc;
  }
}

// ---------------------------------------------------------------------------
// Workspace (~199 MiB): Whh hi/lo 64 | Wih hi/lo 64 | inp hi/lo 32 |
// Xh hi/lo 32.1 (257 slots) | Wq/Wr hi/lo 2 | Wall/RVall/QS 4.5 | bar
// ---------------------------------------------------------------------------
extern "C" void kernel_launch(void* const* d_in, const int* in_sizes, int n_in,
                              void* d_out, int out_size, void* d_ws, size_t ws_size,
                              hipStream_t stream)
{
  (void)in_sizes; (void)n_in; (void)out_size; (void)ws_size;
  const float* inp  = (const float*)d_in[0];
  const float* h0   = (const float*)d_in[1];
  const float* c0   = (const float*)d_in[2];
  const float* F0   = (const float*)d_in[3];
  const float* Wih  = (const float*)d_in[4];
  const float* Whh  = (const float*)d_in[5];
  const float* bih  = (const float*)d_in[6];
  const float* bhh  = (const float*)d_in[7];
  const float* Www  = (const float*)d_in[8];
  const float* Wwb  = (const float*)d_in[9];
  const float* Wrw  = (const float*)d_in[10];
  const float* Wrb  = (const float*)d_in[11];
  const float* Wlin = (const float*)d_in[12];
  const float* blin = (const float*)d_in[13];
  float* out = (float*)d_out;

  char* p = (char*)d_ws;
  auto alloc = [&](size_t bytes) {
    char* r = p;
    p += (bytes + 255) & ~(size_t)255;
    return r;
  };
  bf16*  Whh_hi = (bf16*)alloc(16777216ull * 2);
  bf16*  Whh_lo = (bf16*)alloc(16777216ull * 2);
  bf16*  Wih_hi = (bf16*)alloc(16777216ull * 2);
  bf16*  Wih_lo = (bf16*)alloc(16777216ull * 2);
  bf16*  inp_hi = (bf16*)alloc(8388608ull * 2);
  bf16*  inp_lo = (bf16*)alloc(8388608ull * 2);
  bf16*  XhHi   = (bf16*)alloc(257ull * 32768 * 2);   // slot s = h after s steps
  bf16*  XhLo   = (bf16*)alloc(257ull * 32768 * 2);
  bf16*  Wq_hi  = (bf16*)alloc(262144ull * 2);
  bf16*  Wq_lo  = (bf16*)alloc(262144ull * 2);
  bf16*  Wr_hi  = (bf16*)alloc(262144ull * 2);
  bf16*  Wr_lo  = (bf16*)alloc(262144ull * 2);
  float* wbpad  = (float*)alloc(128ull * 4);
  float* Wall   = (float*)alloc(524288ull * 4);
  float* RVall  = (float*)alloc(524288ull * 4);
  float* QS     = (float*)alloc(131072ull * 4);
  int*   bar    = (int*)alloc(256);

  prep_kernel<<<2048, 256, 0, stream>>>(Wih, Whh, inp, Www, Wwb, Wrw, h0,
                                        Wih_hi, Wih_lo, Whh_hi, Whh_lo,
                                        inp_hi, inp_lo,
                                        Wq_hi, Wq_lo, Wr_hi, Wr_lo, wbpad,
                                        XhHi, XhLo);

  // Phase A+B fused: persistent cooperative LSTM (weights register-resident)
  hipMemsetAsync(bar, 0, 256, stream);
  {
    void* kargs[] = {
      (void*)&Whh_hi, (void*)&Whh_lo, (void*)&Wih_hi, (void*)&Wih_lo,
      (void*)&inp_hi, (void*)&inp_lo, (void*)&bih, (void*)&bhh, (void*)&c0,
      (void*)&XhHi, (void*)&XhLo, (void*)&bar
    };
    hipLaunchCooperativeKernel((const void*)lstm_persist, dim3(NWG), dim3(1024),
                               kargs, 0, stream);
  }

  const bf16* Xb_hi = XhHi + 32768;   // slots 1..256 = x (LSTM outputs)
  const bf16* Xb_lo = XhLo + 32768;

  // Phase C: FWM projections (~fp32 via split-bf16)
  gemm_nt3<1><<<dim3(32, 1), 256, 0, stream>>>(Xb_hi, Xb_lo, Wq_hi, Wq_lo, wbpad,
                                               Wall, MROWS, 128, 2048);
  gemm_nt3<2><<<dim3(32, 1), 256, 0, stream>>>(Xb_hi, Xb_lo, Wr_hi, Wr_lo, Wrb,
                                               RVall, MROWS, 128, 2048);

  // Phase D: FWM scan
  fwm_scan<<<16, 1024, 0, stream>>>(Wall, RVall, F0, QS);

  // Phase E: out = x + QS @ Wlin^T + blin
  out_kernel<<<4096, 256, 0, stream>>>(Xb_hi, Xb_lo, QS, Wlin, blin, out);
}

// Round 6
// 9231.772 us; speedup vs baseline: 1.3018x; 1.3018x over previous
//
#include <hip/hip_runtime.h>
#include <hip/hip_bf16.h>
#include <cstdint>
#include <cstddef>

// Problem constants: L=256, B=16, I=2048, H=2048, S=R=T=32
#define L_DIM 256
#define B_DIM 16
#define I_DIM 2048
#define H_DIM 2048
#define G4    8192
#define MROWS 4096
#define NWG   256

typedef __hip_bfloat16 bf16;
typedef __bf16 bf16x8_t __attribute__((ext_vector_type(8)));
typedef _Float16 f16x8_t __attribute__((ext_vector_type(8)));
typedef float f32x4_t   __attribute__((ext_vector_type(4)));

__device__ __forceinline__ bf16 f2b(float f) { return __float2bfloat16(f); }

__device__ __forceinline__ void gl_lds16(const void* g, void* l) {
  __builtin_amdgcn_global_load_lds(
      (const __attribute__((address_space(1))) unsigned int*)g,
      (__attribute__((address_space(3))) unsigned int*)l, 16, 0, 0);
}

__device__ __forceinline__ float sigmoidf_(float x) { return 1.f / (1.f + expf(-x)); }

// ---------------------------------------------------------------------------
// K0: prep — fp16 casts (LSTM path), bf16 hi/lo (FWM weights), h0 fp16
// ---------------------------------------------------------------------------
__global__ void prep_kernel(const float* __restrict__ Wih, const float* __restrict__ Whh,
                            const float* __restrict__ inp, const float* __restrict__ Www,
                            const float* __restrict__ Wwb, const float* __restrict__ Wrw,
                            const float* __restrict__ h0,
                            _Float16* __restrict__ Wih_f, _Float16* __restrict__ Whh_f,
                            _Float16* __restrict__ inp_f,
                            bf16* __restrict__ Wq_hi, bf16* __restrict__ Wq_lo,
                            bf16* __restrict__ Wr_hi, bf16* __restrict__ Wr_lo,
                            float* __restrict__ wbpad,
                            _Float16* __restrict__ Xh0)
{
  size_t idx0 = (size_t)blockIdx.x * blockDim.x + threadIdx.x;
  size_t stride = (size_t)gridDim.x * blockDim.x;
  for (size_t i = idx0; i < 16777216ull; i += stride) {
    Wih_f[i] = (_Float16)Wih[i];
    Whh_f[i] = (_Float16)Whh[i];
  }
  for (size_t i = idx0; i < 8388608ull; i += stride) inp_f[i] = (_Float16)inp[i];
  for (size_t i = idx0; i < 262144ull; i += stride) {
    size_t r = i >> 11;
    float q = (r < 97) ? Www[i] : 0.f;
    bf16 qh = f2b(q);
    Wq_hi[i] = qh;
    Wq_lo[i] = f2b(q - (float)qh);
    float rr = Wrw[i];
    bf16 rh = f2b(rr);
    Wr_hi[i] = rh;
    Wr_lo[i] = f2b(rr - (float)rh);
  }
  for (size_t i = idx0; i < 128ull; i += stride) wbpad[i] = (i < 97) ? Wwb[i] : 0.f;
  for (size_t i = idx0; i < 32768ull; i += stride) Xh0[i] = (_Float16)h0[i];
}

// ---------------------------------------------------------------------------
// K1: fp16 NT GEMM  C(M,N) = A(M,K) * B(N,K)^T + bias[col]  (fp32 out)
// 128x128 tile, BK=32, 256 threads (4 waves), global_load_lds.
// ---------------------------------------------------------------------------
__global__ __launch_bounds__(256) void gemm_f16(const _Float16* __restrict__ A,
                                                const _Float16* __restrict__ B,
                                                const float* __restrict__ bih,
                                                const float* __restrict__ bhh,
                                                float* __restrict__ C,
                                                int M, int N, int K)
{
  __shared__ __align__(16) _Float16 As[128 * 32];
  __shared__ __align__(16) _Float16 Bs[128 * 32];
  const int tid  = threadIdx.x;
  const int lane = tid & 63;
  const int w    = tid >> 6;
  const int wm   = w >> 1, wn = w & 1;
  const int m0   = blockIdx.x * 128, n0 = blockIdx.y * 128;

  f32x4_t acc[4][4];
#pragma unroll
  for (int m = 0; m < 4; ++m)
#pragma unroll
    for (int n = 0; n < 4; ++n) acc[m][n] = (f32x4_t){0.f, 0.f, 0.f, 0.f};

  for (int k0 = 0; k0 < K; k0 += 32) {
#pragma unroll
    for (int r = 0; r < 2; ++r) {
      const int base = w * 2048 + r * 1024;
      const int off  = base + lane * 16;
      const int e    = off >> 1;
      const int row  = e >> 5;
      const int col  = e & 31;
      gl_lds16(A + (size_t)(m0 + row) * K + (k0 + col), (char*)As + base);
      gl_lds16(B + (size_t)(n0 + row) * K + (k0 + col), (char*)Bs + base);
    }
    __syncthreads();

    f16x8_t af[4], bfr[4];
    const int kb = (lane >> 4) * 16;
#pragma unroll
    for (int m = 0; m < 4; ++m)
      af[m] = *reinterpret_cast<const f16x8_t*>((const char*)As + (wm * 64 + m * 16 + (lane & 15)) * 64 + kb);
#pragma unroll
    for (int n = 0; n < 4; ++n)
      bfr[n] = *reinterpret_cast<const f16x8_t*>((const char*)Bs + (wn * 64 + n * 16 + (lane & 15)) * 64 + kb);
#pragma unroll
    for (int m = 0; m < 4; ++m)
#pragma unroll
      for (int n = 0; n < 4; ++n)
        acc[m][n] = __builtin_amdgcn_mfma_f32_16x16x32_f16(af[m], bfr[n], acc[m][n], 0, 0, 0);
    __syncthreads();
  }

#pragma unroll
  for (int m = 0; m < 4; ++m) {
#pragma unroll
    for (int n = 0; n < 4; ++n) {
      const int col = n0 + wn * 64 + n * 16 + (lane & 15);
      const float bv = bih[col] + bhh[col];
#pragma unroll
      for (int r = 0; r < 4; ++r) {
        const int row = m0 + wm * 64 + m * 16 + (lane >> 4) * 4 + r;
        C[(size_t)row * N + col] = acc[m][n][r] + bv;
      }
    }
  }
}

// ---------------------------------------------------------------------------
// K2: persistent LSTM. 256 WGs x 512 thr (8 waves), cooperative.
// WG owns 8 hidden units (32 gate rows); wave wv owns K-slice [256*wv,+256).
// W_hh fp16 fragments register-resident: 16 frags x 16B = 64 VGPR/lane.
// Per step: 16 MFMAs/wave; LDS reduce; gates on 128 thr (c in registers);
// h -> fp16 (recurrence) + bf16 hi/lo (FWM/out); grid barrier.
// ---------------------------------------------------------------------------
__global__ __launch_bounds__(512, 2) void lstm_persist(
    const _Float16* __restrict__ Whh,
    const float* __restrict__ Gin,
    const float* __restrict__ bih, const float* __restrict__ bhh,
    const float* __restrict__ c0,
    _Float16* __restrict__ Xh,          // 257 slots (16,2048) fp16
    bf16* __restrict__ XhHi, bf16* __restrict__ XhLo,  // 256 slots
    int* bar)
{
  const int tid  = threadIdx.x;
  const int lane = tid & 63;
  const int wv   = tid >> 6;          // 0..7
  const int wg   = blockIdx.x;        // 0..255
  const int j0   = wg * 8;
  const int kw   = wv * 256;

  __shared__ float part[8][2][16][17];   // padded: conflict-free reduce

  // ---- register-resident W_hh fragments (B-operand layout) ----
  f16x8_t whh[2][8];
  {
    const int nn  = lane & 15;
    const int kfo = (lane >> 4) * 8;
#pragma unroll
    for (int nt = 0; nt < 2; ++nt) {
      const int n = nt * 16 + nn;
      const int gate = n >> 3, jj = n & 7;
      const size_t grow = (size_t)(gate * H_DIM + j0 + jj) * 2048;
#pragma unroll
      for (int ks = 0; ks < 8; ++ks)
        whh[nt][ks] = *reinterpret_cast<const f16x8_t*>(Whh + grow + kw + ks * 32 + kfo);
    }
  }

  // ---- per-thread cell state + bias (threads 0..127) ----
  float c_reg = 0.f, cbr0 = 0.f, cbr1 = 0.f, cbr2 = 0.f, cbr3 = 0.f;
  if (tid < 128) {
    const int bb = tid & 15, jj = tid >> 4;
    const int j = j0 + jj;
    c_reg = c0[bb * H_DIM + j];
    cbr0 = bih[0 * H_DIM + j] + bhh[0 * H_DIM + j];
    cbr1 = bih[1 * H_DIM + j] + bhh[1 * H_DIM + j];
    cbr2 = bih[2 * H_DIM + j] + bhh[2 * H_DIM + j];
    cbr3 = bih[3 * H_DIM + j] + bhh[3 * H_DIM + j];
  }

  const size_t arow = (size_t)(lane & 15) * 2048 + kw + (lane >> 4) * 8;

  for (int t = 0; t < L_DIM; ++t) {
    // Gin for this step (hidden under MFMA latency)
    float gin0 = 0.f, gin1 = 0.f, gin2 = 0.f, gin3 = 0.f;
    if (tid < 128) {
      const int bb = tid & 15, jj = tid >> 4;
      const size_t gb = ((size_t)t * 16 + bb) * G4 + j0 + jj;
      gin0 = Gin[gb + 0 * H_DIM];
      gin1 = Gin[gb + 1 * H_DIM];
      gin2 = Gin[gb + 2 * H_DIM];
      gin3 = Gin[gb + 3 * H_DIM];
    }

    // h fragments from Xh slot t
    const size_t hoff = (size_t)t * 32768 + arow;
    f16x8_t hf[8];
#pragma unroll
    for (int ks = 0; ks < 8; ++ks)
      hf[ks] = *reinterpret_cast<const f16x8_t*>(Xh + hoff + ks * 32);

    f32x4_t acc0 = {0.f, 0.f, 0.f, 0.f}, acc1 = {0.f, 0.f, 0.f, 0.f};
#pragma unroll
    for (int ks = 0; ks < 8; ++ks) {
      acc0 = __builtin_amdgcn_mfma_f32_16x16x32_f16(hf[ks], whh[0][ks], acc0, 0, 0, 0);
      acc1 = __builtin_amdgcn_mfma_f32_16x16x32_f16(hf[ks], whh[1][ks], acc1, 0, 0, 0);
    }
#pragma unroll
    for (int r = 0; r < 4; ++r) {
      part[wv][0][(lane >> 4) * 4 + r][lane & 15] = acc0[r];
      part[wv][1][(lane >> 4) * 4 + r][lane & 15] = acc1[r];
    }
    __syncthreads();

    if (tid < 128) {
      const int bb = tid & 15, jj = tid >> 4;
      float g[4] = {gin0, gin1, gin2, gin3};
      const float cb4[4] = {cbr0, cbr1, cbr2, cbr3};
#pragma unroll
      for (int gate = 0; gate < 4; ++gate) {
        const int n = gate * 8 + jj;
        const int ntile = n >> 4, nc = n & 15;
        float s = 0.f;
#pragma unroll
        for (int v = 0; v < 8; ++v) s += part[v][ntile][bb][nc];
        g[gate] += s + cb4[gate];
      }
      const float i_ = sigmoidf_(g[0]);
      const float f_ = sigmoidf_(g[1]);
      const float g_ = tanhf(g[2]);
      const float o_ = sigmoidf_(g[3]);
      c_reg = f_ * c_reg + i_ * g_;
      const float h = o_ * tanhf(c_reg);
      const int bj = bb * 2048 + j0 + jj;
      Xh[(size_t)(t + 1) * 32768 + bj] = (_Float16)h;
      const bf16 hhv = f2b(h);
      const size_t xi = ((size_t)t * 16 + bb) * 2048 + j0 + jj;
      XhHi[xi] = hhv;
      XhLo[xi] = f2b(h - (float)hhv);
    }
    __syncthreads();   // drains all stores (vmcnt 0) + LDS reuse fence

    if (t < L_DIM - 1) {
      if (tid == 0) {
        __threadfence();   // release
        __hip_atomic_fetch_add(bar, 1, __ATOMIC_ACQ_REL, __HIP_MEMORY_SCOPE_AGENT);
        const int target = (t + 1) * NWG;
        while (__hip_atomic_load(bar, __ATOMIC_RELAXED, __HIP_MEMORY_SCOPE_AGENT) < target)
          __builtin_amdgcn_s_sleep(2);
        __threadfence();   // acquire
      }
      __syncthreads();
    }
  }
}

// ---------------------------------------------------------------------------
// K3: split-bf16 (hi+lo) NT GEMM — ~fp32 via 3 products (FWM projections).
// MODE 1: C = acc + bias ; MODE 2: C = tanh(acc + bias)
// ---------------------------------------------------------------------------
template <int MODE>
__global__ __launch_bounds__(256) void gemm_nt3(const bf16* __restrict__ A_hi,
                                                const bf16* __restrict__ A_lo,
                                                const bf16* __restrict__ B_hi,
                                                const bf16* __restrict__ B_lo,
                                                const float* __restrict__ bias,
                                                float* __restrict__ C,
                                                int M, int N, int K)
{
  __shared__ __align__(16) bf16 As[2][128 * 32];
  __shared__ __align__(16) bf16 Bs[2][128 * 32];
  const int tid  = threadIdx.x;
  const int lane = tid & 63;
  const int w    = tid >> 6;
  const int wm   = w >> 1, wn = w & 1;
  const int m0   = blockIdx.x * 128, n0 = blockIdx.y * 128;

  f32x4_t acc[4][4];
#pragma unroll
  for (int m = 0; m < 4; ++m)
#pragma unroll
    for (int n = 0; n < 4; ++n) acc[m][n] = (f32x4_t){0.f, 0.f, 0.f, 0.f};

  for (int k0 = 0; k0 < K; k0 += 32) {
#pragma unroll
    for (int r = 0; r < 2; ++r) {
      const int base = w * 2048 + r * 1024;
      const int off  = base + lane * 16;
      const int e    = off >> 1;
      const int row  = e >> 5;
      const int col  = e & 31;
      const size_t gA = (size_t)(m0 + row) * K + (k0 + col);
      const size_t gB = (size_t)(n0 + row) * K + (k0 + col);
      gl_lds16(A_hi + gA, (char*)As[0] + base);
      gl_lds16(A_lo + gA, (char*)As[1] + base);
      gl_lds16(B_hi + gB, (char*)Bs[0] + base);
      gl_lds16(B_lo + gB, (char*)Bs[1] + base);
    }
    __syncthreads();

    bf16x8_t afh[4], afl[4], bfh[4], bfl[4];
    const int kb = (lane >> 4) * 16;
#pragma unroll
    for (int m = 0; m < 4; ++m) {
      const int ro = (wm * 64 + m * 16 + (lane & 15)) * 64 + kb;
      afh[m] = *reinterpret_cast<const bf16x8_t*>((const char*)As[0] + ro);
      afl[m] = *reinterpret_cast<const bf16x8_t*>((const char*)As[1] + ro);
    }
#pragma unroll
    for (int n = 0; n < 4; ++n) {
      const int ro = (wn * 64 + n * 16 + (lane & 15)) * 64 + kb;
      bfh[n] = *reinterpret_cast<const bf16x8_t*>((const char*)Bs[0] + ro);
      bfl[n] = *reinterpret_cast<const bf16x8_t*>((const char*)Bs[1] + ro);
    }
#pragma unroll
    for (int m = 0; m < 4; ++m)
#pragma unroll
      for (int n = 0; n < 4; ++n) {
        acc[m][n] = __builtin_amdgcn_mfma_f32_16x16x32_bf16(afh[m], bfh[n], acc[m][n], 0, 0, 0);
        acc[m][n] = __builtin_amdgcn_mfma_f32_16x16x32_bf16(afh[m], bfl[n], acc[m][n], 0, 0, 0);
        acc[m][n] = __builtin_amdgcn_mfma_f32_16x16x32_bf16(afl[m], bfh[n], acc[m][n], 0, 0, 0);
      }
    __syncthreads();
  }

#pragma unroll
  for (int m = 0; m < 4; ++m) {
#pragma unroll
    for (int n = 0; n < 4; ++n) {
      const int col = n0 + wn * 64 + n * 16 + (lane & 15);
      const float bv = bias[col];
#pragma unroll
      for (int r = 0; r < 4; ++r) {
        const int row = m0 + wm * 64 + m * 16 + (lane >> 4) * 4 + r;
        float v = acc[m][n][r] + bv;
        if (MODE == 2) v = tanhf(v);
        C[(size_t)row * N + col] = v;
      }
    }
  }
}

// ---------------------------------------------------------------------------
// K4: FWM scan. 16 WGs (one per batch) x 1024 thr. Fm register-resident.
// ---------------------------------------------------------------------------
__global__ __launch_bounds__(1024) void fwm_scan(const float* __restrict__ Wall,   // (4096,128)
                                                 const float* __restrict__ RVall,  // (4096,128)
                                                 const float* __restrict__ F0,     // (16,1024,32)
                                                 float* __restrict__ QS)           // (4096,32)
{
  const int b    = blockIdx.x;
  const int tid  = threadIdx.x;
  const int lane = tid & 63;
  const int wv   = tid >> 6;

  __shared__ float s_s[32], s_r[32], s_tv[32], s_bb;
  __shared__ float s_rv[128];
  __shared__ float s_v[32], s_u[32], s_q[32];
  __shared__ float s_red[16];
  __shared__ float s_inv;

  float F[16][2];
#pragma unroll
  for (int i = 0; i < 16; ++i)
#pragma unroll
    for (int j = 0; j < 2; ++j)
      F[i][j] = F0[((size_t)b * 1024 + (16 * lane + i)) * 32 + 2 * wv + j];

  const int si    = lane >> 1;
  const int rbase = 16 * (lane & 1);

  for (int t = 0; t < 256; ++t) {
    const float* wrow  = Wall  + (size_t)(t * 16 + b) * 128;
    const float* rvrow = RVall + (size_t)(t * 16 + b) * 128;
    __syncthreads();
    if (tid < 32)            s_s[tid]        = tanhf(wrow[tid]);
    else if (tid < 64)       s_r[tid - 32]   = tanhf(wrow[tid]);
    else if (tid < 96)       s_tv[tid - 64]  = tanhf(wrow[tid]);
    else if (tid == 96)      s_bb            = sigmoidf_(wrow[96] + 1.f);
    else if (tid >= 128 && tid < 256) s_rv[tid - 128] = rvrow[tid - 128];
    __syncthreads();

    const float sv = s_s[si];
    float sr[16];
#pragma unroll
    for (int i = 0; i < 16; ++i) sr[i] = sv * s_r[rbase + i];

    float p0 = 0.f, p1 = 0.f;
#pragma unroll
    for (int i = 0; i < 16; ++i) { p0 += sr[i] * F[i][0]; p1 += sr[i] * F[i][1]; }
#pragma unroll
    for (int m = 1; m < 64; m <<= 1) { p0 += __shfl_xor(p0, m); p1 += __shfl_xor(p1, m); }
    if (lane == 0) { s_v[2 * wv] = p0; s_v[2 * wv + 1] = p1; }
    __syncthreads();

    if (tid < 32) s_u[tid] = s_bb * (s_tv[tid] - s_v[tid]);
    __syncthreads();

    const float u0 = s_u[2 * wv], u1 = s_u[2 * wv + 1];
    float nn = 0.f;
#pragma unroll
    for (int i = 0; i < 16; ++i) {
      F[i][0] += sr[i] * u0;
      F[i][1] += sr[i] * u1;
      nn += F[i][0] * F[i][0] + F[i][1] * F[i][1];
    }
#pragma unroll
    for (int m = 1; m < 64; m <<= 1) nn += __shfl_xor(nn, m);
    if (lane == 0) s_red[wv] = nn;
    __syncthreads();
    if (tid == 0) {
      float tot = 0.f;
#pragma unroll
      for (int k = 0; k < 16; ++k) tot += s_red[k];
      const float n_ = sqrtf(tot);
      const float d  = fmaxf(n_ - 1.f, 0.f) + 1.f;
      s_inv = 1.f / d;
    }
    __syncthreads();
    const float inv = s_inv;
#pragma unroll
    for (int i = 0; i < 16; ++i) { F[i][0] *= inv; F[i][1] *= inv; }

#pragma unroll 1
    for (int jit = 0; jit < 3; ++jit) {
      const float qv = (jit == 0) ? s_rv[si] : s_q[si];
      float c0 = 0.f, c1 = 0.f;
#pragma unroll
      for (int i = 0; i < 16; ++i) {
        const float cf = qv * s_rv[32 + 32 * jit + rbase + i];
        c0 += cf * F[i][0];
        c1 += cf * F[i][1];
      }
#pragma unroll
      for (int m = 1; m < 64; m <<= 1) { c0 += __shfl_xor(c0, m); c1 += __shfl_xor(c1, m); }
      if (lane == 0) { s_v[2 * wv] = c0; s_v[2 * wv + 1] = c1; }
      __syncthreads();
      if (wv == 0 && lane < 32) {
        const float x = s_v[lane];
        float mval = x;
#pragma unroll
        for (int m = 1; m < 32; m <<= 1) mval += __shfl_xor(mval, m);
        mval *= (1.f / 32.f);
        const float dl = x - mval;
        float var = dl * dl;
#pragma unroll
        for (int m = 1; m < 32; m <<= 1) var += __shfl_xor(var, m);
        var *= (1.f / 32.f);
        s_q[lane] = dl * rsqrtf(var + 1e-5f);
      }
      __syncthreads();
    }
    if (wv == 0 && lane < 32) QS[(size_t)(t * 16 + b) * 32 + lane] = s_q[lane];
  }
}

// ---------------------------------------------------------------------------
// K5: out = (XhHi+XhLo) + QS @ Wlin^T + blin
// ---------------------------------------------------------------------------
__global__ __launch_bounds__(256) void out_kernel(const bf16* __restrict__ Xh1Hi,
                                                  const bf16* __restrict__ Xh1Lo,
                                                  const float* __restrict__ QS,
                                                  const float* __restrict__ Wlin,  // (2048,32)
                                                  const float* __restrict__ blin,
                                                  float* __restrict__ out)
{
  __shared__ float qs[32];
  const int row = blockIdx.x;
  if (threadIdx.x < 32) qs[threadIdx.x] = QS[(size_t)row * 32 + threadIdx.x];
  __syncthreads();
  for (int h = threadIdx.x; h < H_DIM; h += 256) {
    const size_t xi = (size_t)row * H_DIM + h;
    float acc = (float)Xh1Hi[xi] + (float)Xh1Lo[xi] + blin[h];
    const float* wr = Wlin + (size_t)h * 32;
#pragma unroll
    for (int t2 = 0; t2 < 32; ++t2) acc += qs[t2] * wr[t2];
    out[xi] = acc;
  }
}

// ---------------------------------------------------------------------------
// Workspace (~237 MB), lifetime-aliased:
//  Whh_f16 33.5 | Wih_f16 33.5 (XhLo aliases after Gin GEMM) |
//  inp_f16 16.8 (XhHi aliases) | Gin 134 (Wall/RVall/QS alias after persist) |
//  Xh_f16 16.9 | Wq/Wr hi/lo 2.1 | smalls
// ---------------------------------------------------------------------------
extern "C" void kernel_launch(void* const* d_in, const int* in_sizes, int n_in,
                              void* d_out, int out_size, void* d_ws, size_t ws_size,
                              hipStream_t stream)
{
  (void)in_sizes; (void)n_in; (void)out_size; (void)ws_size;
  const float* inp  = (const float*)d_in[0];
  const float* h0   = (const float*)d_in[1];
  const float* c0   = (const float*)d_in[2];
  const float* F0   = (const float*)d_in[3];
  const float* Wih  = (const float*)d_in[4];
  const float* Whh  = (const float*)d_in[5];
  const float* bih  = (const float*)d_in[6];
  const float* bhh  = (const float*)d_in[7];
  const float* Www  = (const float*)d_in[8];
  const float* Wwb  = (const float*)d_in[9];
  const float* Wrw  = (const float*)d_in[10];
  const float* Wrb  = (const float*)d_in[11];
  const float* Wlin = (const float*)d_in[12];
  const float* blin = (const float*)d_in[13];
  float* out = (float*)d_out;

  char* p = (char*)d_ws;
  auto alloc = [&](size_t bytes) {
    char* r = p;
    p += (bytes + 255) & ~(size_t)255;
    return r;
  };
  _Float16* Whh_f = (_Float16*)alloc(16777216ull * 2);   // 33.5 MB
  _Float16* Wih_f = (_Float16*)alloc(16777216ull * 2);   // 33.5 MB
  _Float16* inp_f = (_Float16*)alloc(8388608ull * 2);    // 16.8 MB
  float*    Gin   = (float*)alloc(33554432ull * 4);      // 134 MB (4096x8192)
  _Float16* Xh    = (_Float16*)alloc(257ull * 32768 * 2);// 16.9 MB
  bf16*  Wq_hi  = (bf16*)alloc(262144ull * 2);
  bf16*  Wq_lo  = (bf16*)alloc(262144ull * 2);
  bf16*  Wr_hi  = (bf16*)alloc(262144ull * 2);
  bf16*  Wr_lo  = (bf16*)alloc(262144ull * 2);
  float* wbpad  = (float*)alloc(128ull * 4);
  int*   bar    = (int*)alloc(256);
  // aliases (strictly later lifetimes):
  bf16*  XhHi  = (bf16*)inp_f;          // 16.8 MB, written by persist after Gin GEMM consumed inp_f
  bf16*  XhLo  = (bf16*)Wih_f;          // 16.8 MB (of 33.5), written after Wih consumed
  float* Wall  = Gin;                   // 2 MB, written after persist consumed Gin
  float* RVall = Gin + 524288;          // 2 MB
  float* QS    = Gin + 1048576;         // 0.5 MB

  prep_kernel<<<2048, 256, 0, stream>>>(Wih, Whh, inp, Www, Wwb, Wrw, h0,
                                        Wih_f, Whh_f, inp_f,
                                        Wq_hi, Wq_lo, Wr_hi, Wr_lo, wbpad, Xh);

  // Phase A: Gin = x @ W_ih^T + (b_ih + b_hh)   (fp16 inputs, fp32 out)
  gemm_f16<<<dim3(32, 64), 256, 0, stream>>>(inp_f, Wih_f, bih, bhh, Gin,
                                             MROWS, G4, 2048);

  // Phase B: persistent cooperative LSTM (W_hh register-resident, fp16)
  hipMemsetAsync(bar, 0, 256, stream);
  {
    void* kargs[] = {
      (void*)&Whh_f, (void*)&Gin, (void*)&bih, (void*)&bhh, (void*)&c0,
      (void*)&Xh, (void*)&XhHi, (void*)&XhLo, (void*)&bar
    };
    hipLaunchCooperativeKernel((const void*)lstm_persist, dim3(NWG), dim3(512),
                               kargs, 0, stream);
  }

  // Phase C: FWM projections (~fp32 via split-bf16)
  gemm_nt3<1><<<dim3(32, 1), 256, 0, stream>>>(XhHi, XhLo, Wq_hi, Wq_lo, wbpad,
                                               Wall, MROWS, 128, 2048);
  gemm_nt3<2><<<dim3(32, 1), 256, 0, stream>>>(XhHi, XhLo, Wr_hi, Wr_lo, Wrb,
                                               RVall, MROWS, 128, 2048);

  // Phase D: FWM scan
  fwm_scan<<<16, 1024, 0, stream>>>(Wall, RVall, F0, QS);

  // Phase E: out = x + QS @ Wlin^T + blin
  out_kernel<<<4096, 256, 0, stream>>>(XhHi, XhLo, QS, Wlin, blin, out);
}

// Round 7
// 8210.193 us; speedup vs baseline: 1.4638x; 1.1244x over previous
//
#include <hip/hip_runtime.h>
#include <hip/hip_bf16.h>
#include <cstdint>
#include <cstddef>

// Problem constants: L=256, B=16, I=2048, H=2048, S=R=T=32
#define L_DIM 256
#define B_DIM 16
#define I_DIM 2048
#define H_DIM 2048
#define G4    8192
#define MROWS 4096
#define NWG   256

typedef __hip_bfloat16 bf16;
typedef __bf16 bf16x8_t __attribute__((ext_vector_type(8)));
typedef _Float16 f16x8_t __attribute__((ext_vector_type(8)));
typedef float f32x4_t   __attribute__((ext_vector_type(4)));

__device__ __forceinline__ bf16 f2b(float f) { return __float2bfloat16(f); }

__device__ __forceinline__ void gl_lds16(const void* g, void* l) {
  __builtin_amdgcn_global_load_lds(
      (const __attribute__((address_space(1))) unsigned int*)g,
      (__attribute__((address_space(3))) unsigned int*)l, 16, 0, 0);
}

__device__ __forceinline__ float sigmoidf_(float x) { return 1.f / (1.f + expf(-x)); }

// ---------------------------------------------------------------------------
// K0: prep — fp16 casts (LSTM path), bf16 hi/lo (FWM weights), h0 fp16
// ---------------------------------------------------------------------------
__global__ void prep_kernel(const float* __restrict__ Wih, const float* __restrict__ Whh,
                            const float* __restrict__ inp, const float* __restrict__ Www,
                            const float* __restrict__ Wwb, const float* __restrict__ Wrw,
                            const float* __restrict__ h0,
                            _Float16* __restrict__ Wih_f, _Float16* __restrict__ Whh_f,
                            _Float16* __restrict__ inp_f,
                            bf16* __restrict__ Wq_hi, bf16* __restrict__ Wq_lo,
                            bf16* __restrict__ Wr_hi, bf16* __restrict__ Wr_lo,
                            float* __restrict__ wbpad,
                            _Float16* __restrict__ Xh0)
{
  size_t idx0 = (size_t)blockIdx.x * blockDim.x + threadIdx.x;
  size_t stride = (size_t)gridDim.x * blockDim.x;
  for (size_t i = idx0; i < 16777216ull; i += stride) {
    Wih_f[i] = (_Float16)Wih[i];
    Whh_f[i] = (_Float16)Whh[i];
  }
  for (size_t i = idx0; i < 8388608ull; i += stride) inp_f[i] = (_Float16)inp[i];
  for (size_t i = idx0; i < 262144ull; i += stride) {
    size_t r = i >> 11;
    float q = (r < 97) ? Www[i] : 0.f;
    bf16 qh = f2b(q);
    Wq_hi[i] = qh;
    Wq_lo[i] = f2b(q - (float)qh);
    float rr = Wrw[i];
    bf16 rh = f2b(rr);
    Wr_hi[i] = rh;
    Wr_lo[i] = f2b(rr - (float)rh);
  }
  for (size_t i = idx0; i < 128ull; i += stride) wbpad[i] = (i < 97) ? Wwb[i] : 0.f;
  for (size_t i = idx0; i < 32768ull; i += stride) Xh0[i] = (_Float16)h0[i];
}

// ---------------------------------------------------------------------------
// K1: fp16 NT GEMM  C(M,N) = A(M,K) * B(N,K)^T + bias[col]  (fp32 out)
// ---------------------------------------------------------------------------
__global__ __launch_bounds__(256) void gemm_f16(const _Float16* __restrict__ A,
                                                const _Float16* __restrict__ B,
                                                const float* __restrict__ bih,
                                                const float* __restrict__ bhh,
                                                float* __restrict__ C,
                                                int M, int N, int K)
{
  __shared__ __align__(16) _Float16 As[128 * 32];
  __shared__ __align__(16) _Float16 Bs[128 * 32];
  const int tid  = threadIdx.x;
  const int lane = tid & 63;
  const int w    = tid >> 6;
  const int wm   = w >> 1, wn = w & 1;
  const int m0   = blockIdx.x * 128, n0 = blockIdx.y * 128;

  f32x4_t acc[4][4];
#pragma unroll
  for (int m = 0; m < 4; ++m)
#pragma unroll
    for (int n = 0; n < 4; ++n) acc[m][n] = (f32x4_t){0.f, 0.f, 0.f, 0.f};

  for (int k0 = 0; k0 < K; k0 += 32) {
#pragma unroll
    for (int r = 0; r < 2; ++r) {
      const int base = w * 2048 + r * 1024;
      const int off  = base + lane * 16;
      const int e    = off >> 1;
      const int row  = e >> 5;
      const int col  = e & 31;
      gl_lds16(A + (size_t)(m0 + row) * K + (k0 + col), (char*)As + base);
      gl_lds16(B + (size_t)(n0 + row) * K + (k0 + col), (char*)Bs + base);
    }
    __syncthreads();

    f16x8_t af[4], bfr[4];
    const int kb = (lane >> 4) * 16;
#pragma unroll
    for (int m = 0; m < 4; ++m)
      af[m] = *reinterpret_cast<const f16x8_t*>((const char*)As + (wm * 64 + m * 16 + (lane & 15)) * 64 + kb);
#pragma unroll
    for (int n = 0; n < 4; ++n)
      bfr[n] = *reinterpret_cast<const f16x8_t*>((const char*)Bs + (wn * 64 + n * 16 + (lane & 15)) * 64 + kb);
#pragma unroll
    for (int m = 0; m < 4; ++m)
#pragma unroll
      for (int n = 0; n < 4; ++n)
        acc[m][n] = __builtin_amdgcn_mfma_f32_16x16x32_f16(af[m], bfr[n], acc[m][n], 0, 0, 0);
    __syncthreads();
  }

#pragma unroll
  for (int m = 0; m < 4; ++m) {
#pragma unroll
    for (int n = 0; n < 4; ++n) {
      const int col = n0 + wn * 64 + n * 16 + (lane & 15);
      const float bv = bih[col] + bhh[col];
#pragma unroll
      for (int r = 0; r < 4; ++r) {
        const int row = m0 + wm * 64 + m * 16 + (lane >> 4) * 4 + r;
        C[(size_t)row * N + col] = acc[m][n][r] + bv;
      }
    }
  }
}

// ---------------------------------------------------------------------------
// K2: persistent LSTM. 256 WGs x 512 thr (8 waves), cooperative.
// W_hh fp16 fragments register-resident. Grid barrier = FLAG ARRAY (one
// 64B line per WG, monotonic step values) — replaces the single-counter
// fetch_add barrier whose 256 serialized cross-XCD RMWs cost ~26 µs/step.
// ---------------------------------------------------------------------------
__global__ __launch_bounds__(512, 2) void lstm_persist(
    const _Float16* __restrict__ Whh,
    const float* __restrict__ Gin,
    const float* __restrict__ bih, const float* __restrict__ bhh,
    const float* __restrict__ c0,
    _Float16* __restrict__ Xh,          // 257 slots (16,2048) fp16
    bf16* __restrict__ XhHi, bf16* __restrict__ XhLo,  // 256 slots
    int* flags)                          // NWG x 16 ints (64B stride)
{
  const int tid  = threadIdx.x;
  const int lane = tid & 63;
  const int wv   = tid >> 6;          // 0..7
  const int wg   = blockIdx.x;        // 0..255
  const int j0   = wg * 8;
  const int kw   = wv * 256;

  __shared__ float part[8][2][16][17];   // padded: conflict-free reduce

  // ---- register-resident W_hh fragments (B-operand layout) ----
  f16x8_t whh[2][8];
  {
    const int nn  = lane & 15;
    const int kfo = (lane >> 4) * 8;
#pragma unroll
    for (int nt = 0; nt < 2; ++nt) {
      const int n = nt * 16 + nn;
      const int gate = n >> 3, jj = n & 7;
      const size_t grow = (size_t)(gate * H_DIM + j0 + jj) * 2048;
#pragma unroll
      for (int ks = 0; ks < 8; ++ks)
        whh[nt][ks] = *reinterpret_cast<const f16x8_t*>(Whh + grow + kw + ks * 32 + kfo);
    }
  }

  // ---- per-thread cell state + bias (threads 0..127) ----
  float c_reg = 0.f, cbr0 = 0.f, cbr1 = 0.f, cbr2 = 0.f, cbr3 = 0.f;
  if (tid < 128) {
    const int bb = tid & 15, jj = tid >> 4;
    const int j = j0 + jj;
    c_reg = c0[bb * H_DIM + j];
    cbr0 = bih[0 * H_DIM + j] + bhh[0 * H_DIM + j];
    cbr1 = bih[1 * H_DIM + j] + bhh[1 * H_DIM + j];
    cbr2 = bih[2 * H_DIM + j] + bhh[2 * H_DIM + j];
    cbr3 = bih[3 * H_DIM + j] + bhh[3 * H_DIM + j];
  }

  const size_t arow = (size_t)(lane & 15) * 2048 + kw + (lane >> 4) * 8;

  for (int t = 0; t < L_DIM; ++t) {
    // Gin for this step
    float gin0 = 0.f, gin1 = 0.f, gin2 = 0.f, gin3 = 0.f;
    if (tid < 128) {
      const int bb = tid & 15, jj = tid >> 4;
      const size_t gb = ((size_t)t * 16 + bb) * G4 + j0 + jj;
      gin0 = Gin[gb + 0 * H_DIM];
      gin1 = Gin[gb + 1 * H_DIM];
      gin2 = Gin[gb + 2 * H_DIM];
      gin3 = Gin[gb + 3 * H_DIM];
    }

    // h fragments from Xh slot t
    const size_t hoff = (size_t)t * 32768 + arow;
    f16x8_t hf[8];
#pragma unroll
    for (int ks = 0; ks < 8; ++ks)
      hf[ks] = *reinterpret_cast<const f16x8_t*>(Xh + hoff + ks * 32);

    f32x4_t acc0 = {0.f, 0.f, 0.f, 0.f}, acc1 = {0.f, 0.f, 0.f, 0.f};
#pragma unroll
    for (int ks = 0; ks < 8; ++ks) {
      acc0 = __builtin_amdgcn_mfma_f32_16x16x32_f16(hf[ks], whh[0][ks], acc0, 0, 0, 0);
      acc1 = __builtin_amdgcn_mfma_f32_16x16x32_f16(hf[ks], whh[1][ks], acc1, 0, 0, 0);
    }
#pragma unroll
    for (int r = 0; r < 4; ++r) {
      part[wv][0][(lane >> 4) * 4 + r][lane & 15] = acc0[r];
      part[wv][1][(lane >> 4) * 4 + r][lane & 15] = acc1[r];
    }
    __syncthreads();

    if (tid < 128) {
      const int bb = tid & 15, jj = tid >> 4;
      float g[4] = {gin0, gin1, gin2, gin3};
      const float cb4[4] = {cbr0, cbr1, cbr2, cbr3};
#pragma unroll
      for (int gate = 0; gate < 4; ++gate) {
        const int n = gate * 8 + jj;
        const int ntile = n >> 4, nc = n & 15;
        float s = 0.f;
#pragma unroll
        for (int v = 0; v < 8; ++v) s += part[v][ntile][bb][nc];
        g[gate] += s + cb4[gate];
      }
      const float i_ = sigmoidf_(g[0]);
      const float f_ = sigmoidf_(g[1]);
      const float g_ = tanhf(g[2]);
      const float o_ = sigmoidf_(g[3]);
      c_reg = f_ * c_reg + i_ * g_;
      const float h = o_ * tanhf(c_reg);
      const int bj = bb * 2048 + j0 + jj;
      Xh[(size_t)(t + 1) * 32768 + bj] = (_Float16)h;
      const bf16 hhv = f2b(h);
      const size_t xi = ((size_t)t * 16 + bb) * 2048 + j0 + jj;
      XhHi[xi] = hhv;
      XhLo[xi] = f2b(h - (float)hhv);
    }
    __syncthreads();   // drains vmcnt(0): all h stores complete + LDS fence

    if (t < L_DIM - 1) {
      const int target = t + 1;
      if (tid == 0) {
        // release: write back dirty L2 to IC, then publish arrival
        __builtin_amdgcn_fence(__ATOMIC_RELEASE, "agent");
        __hip_atomic_store(&flags[wg << 4], target, __ATOMIC_RELAXED,
                           __HIP_MEMORY_SCOPE_AGENT);
      }
      if (tid < NWG) {
        // poll: 256 independent lines, relaxed agent loads (sc1 -> IC)
        while (__hip_atomic_load(&flags[tid << 4], __ATOMIC_RELAXED,
                                 __HIP_MEMORY_SCOPE_AGENT) < target)
          __builtin_amdgcn_s_sleep(1);
      }
      // acquire: invalidate stale L1/L2 before reading h(t+1)
      __builtin_amdgcn_fence(__ATOMIC_ACQUIRE, "agent");
      __syncthreads();
    }
  }
}

// ---------------------------------------------------------------------------
// K3: split-bf16 (hi+lo) NT GEMM — ~fp32 via 3 products (FWM projections).
// MODE 1: C = acc + bias ; MODE 2: C = tanh(acc + bias)
// ---------------------------------------------------------------------------
template <int MODE>
__global__ __launch_bounds__(256) void gemm_nt3(const bf16* __restrict__ A_hi,
                                                const bf16* __restrict__ A_lo,
                                                const bf16* __restrict__ B_hi,
                                                const bf16* __restrict__ B_lo,
                                                const float* __restrict__ bias,
                                                float* __restrict__ C,
                                                int M, int N, int K)
{
  __shared__ __align__(16) bf16 As[2][128 * 32];
  __shared__ __align__(16) bf16 Bs[2][128 * 32];
  const int tid  = threadIdx.x;
  const int lane = tid & 63;
  const int w    = tid >> 6;
  const int wm   = w >> 1, wn = w & 1;
  const int m0   = blockIdx.x * 128, n0 = blockIdx.y * 128;

  f32x4_t acc[4][4];
#pragma unroll
  for (int m = 0; m < 4; ++m)
#pragma unroll
    for (int n = 0; n < 4; ++n) acc[m][n] = (f32x4_t){0.f, 0.f, 0.f, 0.f};

  for (int k0 = 0; k0 < K; k0 += 32) {
#pragma unroll
    for (int r = 0; r < 2; ++r) {
      const int base = w * 2048 + r * 1024;
      const int off  = base + lane * 16;
      const int e    = off >> 1;
      const int row  = e >> 5;
      const int col  = e & 31;
      const size_t gA = (size_t)(m0 + row) * K + (k0 + col);
      const size_t gB = (size_t)(n0 + row) * K + (k0 + col);
      gl_lds16(A_hi + gA, (char*)As[0] + base);
      gl_lds16(A_lo + gA, (char*)As[1] + base);
      gl_lds16(B_hi + gB, (char*)Bs[0] + base);
      gl_lds16(B_lo + gB, (char*)Bs[1] + base);
    }
    __syncthreads();

    bf16x8_t afh[4], afl[4], bfh[4], bfl[4];
    const int kb = (lane >> 4) * 16;
#pragma unroll
    for (int m = 0; m < 4; ++m) {
      const int ro = (wm * 64 + m * 16 + (lane & 15)) * 64 + kb;
      afh[m] = *reinterpret_cast<const bf16x8_t*>((const char*)As[0] + ro);
      afl[m] = *reinterpret_cast<const bf16x8_t*>((const char*)As[1] + ro);
    }
#pragma unroll
    for (int n = 0; n < 4; ++n) {
      const int ro = (wn * 64 + n * 16 + (lane & 15)) * 64 + kb;
      bfh[n] = *reinterpret_cast<const bf16x8_t*>((const char*)Bs[0] + ro);
      bfl[n] = *reinterpret_cast<const bf16x8_t*>((const char*)Bs[1] + ro);
    }
#pragma unroll
    for (int m = 0; m < 4; ++m)
#pragma unroll
      for (int n = 0; n < 4; ++n) {
        acc[m][n] = __builtin_amdgcn_mfma_f32_16x16x32_bf16(afh[m], bfh[n], acc[m][n], 0, 0, 0);
        acc[m][n] = __builtin_amdgcn_mfma_f32_16x16x32_bf16(afh[m], bfl[n], acc[m][n], 0, 0, 0);
        acc[m][n] = __builtin_amdgcn_mfma_f32_16x16x32_bf16(afl[m], bfh[n], acc[m][n], 0, 0, 0);
      }
    __syncthreads();
  }

#pragma unroll
  for (int m = 0; m < 4; ++m) {
#pragma unroll
    for (int n = 0; n < 4; ++n) {
      const int col = n0 + wn * 64 + n * 16 + (lane & 15);
      const float bv = bias[col];
#pragma unroll
      for (int r = 0; r < 4; ++r) {
        const int row = m0 + wm * 64 + m * 16 + (lane >> 4) * 4 + r;
        float v = acc[m][n][r] + bv;
        if (MODE == 2) v = tanhf(v);
        C[(size_t)row * N + col] = v;
      }
    }
  }
}

// ---------------------------------------------------------------------------
// K4: FWM scan. 16 WGs (one per batch) x 1024 thr. Fm register-resident.
// ---------------------------------------------------------------------------
__global__ __launch_bounds__(1024) void fwm_scan(const float* __restrict__ Wall,   // (4096,128)
                                                 const float* __restrict__ RVall,  // (4096,128)
                                                 const float* __restrict__ F0,     // (16,1024,32)
                                                 float* __restrict__ QS)           // (4096,32)
{
  const int b    = blockIdx.x;
  const int tid  = threadIdx.x;
  const int lane = tid & 63;
  const int wv   = tid >> 6;

  __shared__ float s_s[32], s_r[32], s_tv[32], s_bb;
  __shared__ float s_rv[128];
  __shared__ float s_v[32], s_u[32], s_q[32];
  __shared__ float s_red[16];
  __shared__ float s_inv;

  float F[16][2];
#pragma unroll
  for (int i = 0; i < 16; ++i)
#pragma unroll
    for (int j = 0; j < 2; ++j)
      F[i][j] = F0[((size_t)b * 1024 + (16 * lane + i)) * 32 + 2 * wv + j];

  const int si    = lane >> 1;
  const int rbase = 16 * (lane & 1);

  for (int t = 0; t < 256; ++t) {
    const float* wrow  = Wall  + (size_t)(t * 16 + b) * 128;
    const float* rvrow = RVall + (size_t)(t * 16 + b) * 128;
    __syncthreads();
    if (tid < 32)            s_s[tid]        = tanhf(wrow[tid]);
    else if (tid < 64)       s_r[tid - 32]   = tanhf(wrow[tid]);
    else if (tid < 96)       s_tv[tid - 64]  = tanhf(wrow[tid]);
    else if (tid == 96)      s_bb            = sigmoidf_(wrow[96] + 1.f);
    else if (tid >= 128 && tid < 256) s_rv[tid - 128] = rvrow[tid - 128];
    __syncthreads();

    const float sv = s_s[si];
    float sr[16];
#pragma unroll
    for (int i = 0; i < 16; ++i) sr[i] = sv * s_r[rbase + i];

    float p0 = 0.f, p1 = 0.f;
#pragma unroll
    for (int i = 0; i < 16; ++i) { p0 += sr[i] * F[i][0]; p1 += sr[i] * F[i][1]; }
#pragma unroll
    for (int m = 1; m < 64; m <<= 1) { p0 += __shfl_xor(p0, m); p1 += __shfl_xor(p1, m); }
    if (lane == 0) { s_v[2 * wv] = p0; s_v[2 * wv + 1] = p1; }
    __syncthreads();

    if (tid < 32) s_u[tid] = s_bb * (s_tv[tid] - s_v[tid]);
    __syncthreads();

    const float u0 = s_u[2 * wv], u1 = s_u[2 * wv + 1];
    float nn = 0.f;
#pragma unroll
    for (int i = 0; i < 16; ++i) {
      F[i][0] += sr[i] * u0;
      F[i][1] += sr[i] * u1;
      nn += F[i][0] * F[i][0] + F[i][1] * F[i][1];
    }
#pragma unroll
    for (int m = 1; m < 64; m <<= 1) nn += __shfl_xor(nn, m);
    if (lane == 0) s_red[wv] = nn;
    __syncthreads();
    if (tid == 0) {
      float tot = 0.f;
#pragma unroll
      for (int k = 0; k < 16; ++k) tot += s_red[k];
      const float n_ = sqrtf(tot);
      const float d  = fmaxf(n_ - 1.f, 0.f) + 1.f;
      s_inv = 1.f / d;
    }
    __syncthreads();
    const float inv = s_inv;
#pragma unroll
    for (int i = 0; i < 16; ++i) { F[i][0] *= inv; F[i][1] *= inv; }

#pragma unroll 1
    for (int jit = 0; jit < 3; ++jit) {
      const float qv = (jit == 0) ? s_rv[si] : s_q[si];
      float c0 = 0.f, c1 = 0.f;
#pragma unroll
      for (int i = 0; i < 16; ++i) {
        const float cf = qv * s_rv[32 + 32 * jit + rbase + i];
        c0 += cf * F[i][0];
        c1 += cf * F[i][1];
      }
#pragma unroll
      for (int m = 1; m < 64; m <<= 1) { c0 += __shfl_xor(c0, m); c1 += __shfl_xor(c1, m); }
      if (lane == 0) { s_v[2 * wv] = c0; s_v[2 * wv + 1] = c1; }
      __syncthreads();
      if (wv == 0 && lane < 32) {
        const float x = s_v[lane];
        float mval = x;
#pragma unroll
        for (int m = 1; m < 32; m <<= 1) mval += __shfl_xor(mval, m);
        mval *= (1.f / 32.f);
        const float dl = x - mval;
        float var = dl * dl;
#pragma unroll
        for (int m = 1; m < 32; m <<= 1) var += __shfl_xor(var, m);
        var *= (1.f / 32.f);
        s_q[lane] = dl * rsqrtf(var + 1e-5f);
      }
      __syncthreads();
    }
    if (wv == 0 && lane < 32) QS[(size_t)(t * 16 + b) * 32 + lane] = s_q[lane];
  }
}

// ---------------------------------------------------------------------------
// K5: out = (XhHi+XhLo) + QS @ Wlin^T + blin
// ---------------------------------------------------------------------------
__global__ __launch_bounds__(256) void out_kernel(const bf16* __restrict__ Xh1Hi,
                                                  const bf16* __restrict__ Xh1Lo,
                                                  const float* __restrict__ QS,
                                                  const float* __restrict__ Wlin,  // (2048,32)
                                                  const float* __restrict__ blin,
                                                  float* __restrict__ out)
{
  __shared__ float qs[32];
  const int row = blockIdx.x;
  if (threadIdx.x < 32) qs[threadIdx.x] = QS[(size_t)row * 32 + threadIdx.x];
  __syncthreads();
  for (int h = threadIdx.x; h < H_DIM; h += 256) {
    const size_t xi = (size_t)row * H_DIM + h;
    float acc = (float)Xh1Hi[xi] + (float)Xh1Lo[xi] + blin[h];
    const float* wr = Wlin + (size_t)h * 32;
#pragma unroll
    for (int t2 = 0; t2 < 32; ++t2) acc += qs[t2] * wr[t2];
    out[xi] = acc;
  }
}

// ---------------------------------------------------------------------------
// Workspace (~237 MB), lifetime-aliased:
//  Whh_f16 33.5 | Wih_f16 33.5 (XhLo aliases after Gin GEMM) |
//  inp_f16 16.8 (XhHi aliases) | Gin 134 (Wall/RVall/QS alias after persist) |
//  Xh_f16 16.9 | Wq/Wr hi/lo 2.1 | flags 16KB | smalls
// ---------------------------------------------------------------------------
extern "C" void kernel_launch(void* const* d_in, const int* in_sizes, int n_in,
                              void* d_out, int out_size, void* d_ws, size_t ws_size,
                              hipStream_t stream)
{
  (void)in_sizes; (void)n_in; (void)out_size; (void)ws_size;
  const float* inp  = (const float*)d_in[0];
  const float* h0   = (const float*)d_in[1];
  const float* c0   = (const float*)d_in[2];
  const float* F0   = (const float*)d_in[3];
  const float* Wih  = (const float*)d_in[4];
  const float* Whh  = (const float*)d_in[5];
  const float* bih  = (const float*)d_in[6];
  const float* bhh  = (const float*)d_in[7];
  const float* Www  = (const float*)d_in[8];
  const float* Wwb  = (const float*)d_in[9];
  const float* Wrw  = (const float*)d_in[10];
  const float* Wrb  = (const float*)d_in[11];
  const float* Wlin = (const float*)d_in[12];
  const float* blin = (const float*)d_in[13];
  float* out = (float*)d_out;

  char* p = (char*)d_ws;
  auto alloc = [&](size_t bytes) {
    char* r = p;
    p += (bytes + 255) & ~(size_t)255;
    return r;
  };
  _Float16* Whh_f = (_Float16*)alloc(16777216ull * 2);   // 33.5 MB
  _Float16* Wih_f = (_Float16*)alloc(16777216ull * 2);   // 33.5 MB
  _Float16* inp_f = (_Float16*)alloc(8388608ull * 2);    // 16.8 MB
  float*    Gin   = (float*)alloc(33554432ull * 4);      // 134 MB (4096x8192)
  _Float16* Xh    = (_Float16*)alloc(257ull * 32768 * 2);// 16.9 MB
  bf16*  Wq_hi  = (bf16*)alloc(262144ull * 2);
  bf16*  Wq_lo  = (bf16*)alloc(262144ull * 2);
  bf16*  Wr_hi  = (bf16*)alloc(262144ull * 2);
  bf16*  Wr_lo  = (bf16*)alloc(262144ull * 2);
  float* wbpad  = (float*)alloc(128ull * 4);
  int*   flags  = (int*)alloc(NWG * 64);                 // 64B line per WG
  // aliases (strictly later lifetimes):
  bf16*  XhHi  = (bf16*)inp_f;          // written by persist after Gin GEMM consumed inp_f
  bf16*  XhLo  = (bf16*)Wih_f;          // written after Wih consumed
  float* Wall  = Gin;                   // 2 MB, written after persist consumed Gin
  float* RVall = Gin + 524288;          // 2 MB
  float* QS    = Gin + 1048576;         // 0.5 MB

  prep_kernel<<<2048, 256, 0, stream>>>(Wih, Whh, inp, Www, Wwb, Wrw, h0,
                                        Wih_f, Whh_f, inp_f,
                                        Wq_hi, Wq_lo, Wr_hi, Wr_lo, wbpad, Xh);

  // Phase A: Gin = x @ W_ih^T + (b_ih + b_hh)   (fp16 inputs, fp32 out)
  gemm_f16<<<dim3(32, 64), 256, 0, stream>>>(inp_f, Wih_f, bih, bhh, Gin,
                                             MROWS, G4, 2048);

  // Phase B: persistent cooperative LSTM (W_hh register-resident, fp16)
  hipMemsetAsync(flags, 0, NWG * 64, stream);
  {
    void* kargs[] = {
      (void*)&Whh_f, (void*)&Gin, (void*)&bih, (void*)&bhh, (void*)&c0,
      (void*)&Xh, (void*)&XhHi, (void*)&XhLo, (void*)&flags
    };
    hipLaunchCooperativeKernel((const void*)lstm_persist, dim3(NWG), dim3(512),
                               kargs, 0, stream);
  }

  // Phase C: FWM projections (~fp32 via split-bf16)
  gemm_nt3<1><<<dim3(32, 1), 256, 0, stream>>>(XhHi, XhLo, Wq_hi, Wq_lo, wbpad,
                                               Wall, MROWS, 128, 2048);
  gemm_nt3<2><<<dim3(32, 1), 256, 0, stream>>>(XhHi, XhLo, Wr_hi, Wr_lo, Wrb,
                                               RVall, MROWS, 128, 2048);

  // Phase D: FWM scan
  fwm_scan<<<16, 1024, 0, stream>>>(Wall, RVall, F0, QS);

  // Phase E: out = x + QS @ Wlin^T + blin
  out_kernel<<<4096, 256, 0, stream>>>(XhHi, XhLo, QS, Wlin, blin, out);
}

// Round 8
// 3583.961 us; speedup vs baseline: 3.3533x; 2.2908x over previous
//
#include <hip/hip_runtime.h>
#include <hip/hip_bf16.h>
#include <cstdint>
#include <cstddef>

// Problem constants: L=256, B=16, I=2048, H=2048, S=R=T=32
#define L_DIM 256
#define B_DIM 16
#define I_DIM 2048
#define H_DIM 2048
#define G4    8192
#define MROWS 4096
#define NWG   256

typedef __hip_bfloat16 bf16;
typedef __bf16 bf16x8_t __attribute__((ext_vector_type(8)));
typedef _Float16 f16x8_t __attribute__((ext_vector_type(8)));
typedef float f32x4_t   __attribute__((ext_vector_type(4)));

__device__ __forceinline__ bf16 f2b(float f) { return __float2bfloat16(f); }

__device__ __forceinline__ void gl_lds16(const void* g, void* l) {
  __builtin_amdgcn_global_load_lds(
      (const __attribute__((address_space(1))) unsigned int*)g,
      (__attribute__((address_space(3))) unsigned int*)l, 16, 0, 0);
}

__device__ __forceinline__ float sigmoidf_(float x) { return 1.f / (1.f + expf(-x)); }

// Coherent (IC-through) access helpers — same hardware path the working
// flag protocol uses (sc1 store -> IC, sc1 load <- IC), widened to data.
__device__ __forceinline__ f16x8_t load_f16x8_sc(const _Float16* p) {
  f16x8_t r;
  asm volatile("global_load_dwordx4 %0, %1, off sc0 sc1" : "=v"(r) : "v"(p));
  return r;
}
__device__ __forceinline__ void store_short_sc(void* p, unsigned int v) {
  asm volatile("global_store_short %0, %1, off sc0 sc1" :: "v"(p), "v"(v) : "memory");
}

// ---------------------------------------------------------------------------
// K0: prep — fp16 casts (LSTM path), bf16 hi/lo (FWM weights), h0 fp16
// ---------------------------------------------------------------------------
__global__ void prep_kernel(const float* __restrict__ Wih, const float* __restrict__ Whh,
                            const float* __restrict__ inp, const float* __restrict__ Www,
                            const float* __restrict__ Wwb, const float* __restrict__ Wrw,
                            const float* __restrict__ h0,
                            _Float16* __restrict__ Wih_f, _Float16* __restrict__ Whh_f,
                            _Float16* __restrict__ inp_f,
                            bf16* __restrict__ Wq_hi, bf16* __restrict__ Wq_lo,
                            bf16* __restrict__ Wr_hi, bf16* __restrict__ Wr_lo,
                            float* __restrict__ wbpad,
                            _Float16* __restrict__ Xh0)
{
  size_t idx0 = (size_t)blockIdx.x * blockDim.x + threadIdx.x;
  size_t stride = (size_t)gridDim.x * blockDim.x;
  for (size_t i = idx0; i < 16777216ull; i += stride) {
    Wih_f[i] = (_Float16)Wih[i];
    Whh_f[i] = (_Float16)Whh[i];
  }
  for (size_t i = idx0; i < 8388608ull; i += stride) inp_f[i] = (_Float16)inp[i];
  for (size_t i = idx0; i < 262144ull; i += stride) {
    size_t r = i >> 11;
    float q = (r < 97) ? Www[i] : 0.f;
    bf16 qh = f2b(q);
    Wq_hi[i] = qh;
    Wq_lo[i] = f2b(q - (float)qh);
    float rr = Wrw[i];
    bf16 rh = f2b(rr);
    Wr_hi[i] = rh;
    Wr_lo[i] = f2b(rr - (float)rh);
  }
  for (size_t i = idx0; i < 128ull; i += stride) wbpad[i] = (i < 97) ? Wwb[i] : 0.f;
  for (size_t i = idx0; i < 32768ull; i += stride) Xh0[i] = (_Float16)h0[i];
}

// ---------------------------------------------------------------------------
// K1: fp16 NT GEMM  C(M,N) = A(M,K) * B(N,K)^T + bias[col]  (fp32 out)
// ---------------------------------------------------------------------------
__global__ __launch_bounds__(256) void gemm_f16(const _Float16* __restrict__ A,
                                                const _Float16* __restrict__ B,
                                                const float* __restrict__ bih,
                                                const float* __restrict__ bhh,
                                                float* __restrict__ C,
                                                int M, int N, int K)
{
  __shared__ __align__(16) _Float16 As[128 * 32];
  __shared__ __align__(16) _Float16 Bs[128 * 32];
  const int tid  = threadIdx.x;
  const int lane = tid & 63;
  const int w    = tid >> 6;
  const int wm   = w >> 1, wn = w & 1;
  const int m0   = blockIdx.x * 128, n0 = blockIdx.y * 128;

  f32x4_t acc[4][4];
#pragma unroll
  for (int m = 0; m < 4; ++m)
#pragma unroll
    for (int n = 0; n < 4; ++n) acc[m][n] = (f32x4_t){0.f, 0.f, 0.f, 0.f};

  for (int k0 = 0; k0 < K; k0 += 32) {
#pragma unroll
    for (int r = 0; r < 2; ++r) {
      const int base = w * 2048 + r * 1024;
      const int off  = base + lane * 16;
      const int e    = off >> 1;
      const int row  = e >> 5;
      const int col  = e & 31;
      gl_lds16(A + (size_t)(m0 + row) * K + (k0 + col), (char*)As + base);
      gl_lds16(B + (size_t)(n0 + row) * K + (k0 + col), (char*)Bs + base);
    }
    __syncthreads();

    f16x8_t af[4], bfr[4];
    const int kb = (lane >> 4) * 16;
#pragma unroll
    for (int m = 0; m < 4; ++m)
      af[m] = *reinterpret_cast<const f16x8_t*>((const char*)As + (wm * 64 + m * 16 + (lane & 15)) * 64 + kb);
#pragma unroll
    for (int n = 0; n < 4; ++n)
      bfr[n] = *reinterpret_cast<const f16x8_t*>((const char*)Bs + (wn * 64 + n * 16 + (lane & 15)) * 64 + kb);
#pragma unroll
    for (int m = 0; m < 4; ++m)
#pragma unroll
      for (int n = 0; n < 4; ++n)
        acc[m][n] = __builtin_amdgcn_mfma_f32_16x16x32_f16(af[m], bfr[n], acc[m][n], 0, 0, 0);
    __syncthreads();
  }

#pragma unroll
  for (int m = 0; m < 4; ++m) {
#pragma unroll
    for (int n = 0; n < 4; ++n) {
      const int col = n0 + wn * 64 + n * 16 + (lane & 15);
      const float bv = bih[col] + bhh[col];
#pragma unroll
      for (int r = 0; r < 4; ++r) {
        const int row = m0 + wm * 64 + m * 16 + (lane >> 4) * 4 + r;
        C[(size_t)row * N + col] = acc[m][n][r] + bv;
      }
    }
  }
}

// ---------------------------------------------------------------------------
// K2: persistent LSTM. 256 WGs x 512 thr (8 waves), cooperative.
// W_hh fp16 fragments register-resident. h exchange is FENCE-FREE:
// sc0/sc1 write-through stores (h -> IC) + vmcnt(0) drain + flag array;
// readers use sc0/sc1 loads (IC direct, bypass L1/L2). No buffer_wbl2 /
// buffer_inv per step (round-7 fences cost ~20 us/step).
// ---------------------------------------------------------------------------
__global__ __launch_bounds__(512, 2) void lstm_persist(
    const _Float16* __restrict__ Whh,
    const float* __restrict__ Gin,
    const float* __restrict__ bih, const float* __restrict__ bhh,
    const float* __restrict__ c0,
    _Float16* __restrict__ Xh,          // 257 slots (16,2048) fp16
    bf16* __restrict__ XhHi, bf16* __restrict__ XhLo,  // 256 slots
    int* flags)                          // NWG x 16 ints (64B stride)
{
  const int tid  = threadIdx.x;
  const int lane = tid & 63;
  const int wv   = tid >> 6;          // 0..7
  const int wg   = blockIdx.x;        // 0..255
  const int j0   = wg * 8;
  const int kw   = wv * 256;

  __shared__ float part[8][2][16][17];   // padded: conflict-free reduce

  // ---- register-resident W_hh fragments (B-operand layout) ----
  f16x8_t whh[2][8];
  {
    const int nn  = lane & 15;
    const int kfo = (lane >> 4) * 8;
#pragma unroll
    for (int nt = 0; nt < 2; ++nt) {
      const int n = nt * 16 + nn;
      const int gate = n >> 3, jj = n & 7;
      const size_t grow = (size_t)(gate * H_DIM + j0 + jj) * 2048;
#pragma unroll
      for (int ks = 0; ks < 8; ++ks)
        whh[nt][ks] = *reinterpret_cast<const f16x8_t*>(Whh + grow + kw + ks * 32 + kfo);
    }
  }

  // ---- per-thread cell state + bias (threads 0..127) ----
  float c_reg = 0.f, cbr0 = 0.f, cbr1 = 0.f, cbr2 = 0.f, cbr3 = 0.f;
  if (tid < 128) {
    const int bb = tid & 15, jj = tid >> 4;
    const int j = j0 + jj;
    c_reg = c0[bb * H_DIM + j];
    cbr0 = bih[0 * H_DIM + j] + bhh[0 * H_DIM + j];
    cbr1 = bih[1 * H_DIM + j] + bhh[1 * H_DIM + j];
    cbr2 = bih[2 * H_DIM + j] + bhh[2 * H_DIM + j];
    cbr3 = bih[3 * H_DIM + j] + bhh[3 * H_DIM + j];
  }

  const size_t arow = (size_t)(lane & 15) * 2048 + kw + (lane >> 4) * 8;

  for (int t = 0; t < L_DIM; ++t) {
    // Gin for this step (plain cached loads; written by a prior kernel)
    float gin0 = 0.f, gin1 = 0.f, gin2 = 0.f, gin3 = 0.f;
    if (tid < 128) {
      const int bb = tid & 15, jj = tid >> 4;
      const size_t gb = ((size_t)t * 16 + bb) * G4 + j0 + jj;
      gin0 = Gin[gb + 0 * H_DIM];
      gin1 = Gin[gb + 1 * H_DIM];
      gin2 = Gin[gb + 2 * H_DIM];
      gin3 = Gin[gb + 3 * H_DIM];
    }

    // h fragments from Xh slot t — coherent IC reads (bypass L1/L2)
    const size_t hoff = (size_t)t * 32768 + arow;
    f16x8_t hf[8];
#pragma unroll
    for (int ks = 0; ks < 8; ++ks)
      hf[ks] = load_f16x8_sc(Xh + hoff + ks * 32);
    asm volatile("s_waitcnt vmcnt(0)" ::: "memory");
    __builtin_amdgcn_sched_barrier(0);   // rule #18: keep MFMAs below the wait

    f32x4_t acc0 = {0.f, 0.f, 0.f, 0.f}, acc1 = {0.f, 0.f, 0.f, 0.f};
#pragma unroll
    for (int ks = 0; ks < 8; ++ks) {
      acc0 = __builtin_amdgcn_mfma_f32_16x16x32_f16(hf[ks], whh[0][ks], acc0, 0, 0, 0);
      acc1 = __builtin_amdgcn_mfma_f32_16x16x32_f16(hf[ks], whh[1][ks], acc1, 0, 0, 0);
    }
#pragma unroll
    for (int r = 0; r < 4; ++r) {
      part[wv][0][(lane >> 4) * 4 + r][lane & 15] = acc0[r];
      part[wv][1][(lane >> 4) * 4 + r][lane & 15] = acc1[r];
    }
    __syncthreads();

    if (tid < 128) {
      const int bb = tid & 15, jj = tid >> 4;
      float g[4] = {gin0, gin1, gin2, gin3};
      const float cb4[4] = {cbr0, cbr1, cbr2, cbr3};
#pragma unroll
      for (int gate = 0; gate < 4; ++gate) {
        const int n = gate * 8 + jj;
        const int ntile = n >> 4, nc = n & 15;
        float s = 0.f;
#pragma unroll
        for (int v = 0; v < 8; ++v) s += part[v][ntile][bb][nc];
        g[gate] += s + cb4[gate];
      }
      const float i_ = sigmoidf_(g[0]);
      const float f_ = sigmoidf_(g[1]);
      const float g_ = tanhf(g[2]);
      const float o_ = sigmoidf_(g[3]);
      c_reg = f_ * c_reg + i_ * g_;
      const float h = o_ * tanhf(c_reg);
      const int bj = bb * 2048 + j0 + jj;
      // write-through (IC) stores: fp16 for recurrence, bf16 hi/lo for FWM
      const _Float16 hF = (_Float16)h;
      const bf16 hhv = f2b(h);
      const bf16 hlv = f2b(h - (float)hhv);
      const size_t xi = ((size_t)t * 16 + bb) * 2048 + j0 + jj;
      store_short_sc(Xh + (size_t)(t + 1) * 32768 + bj,
                     (unsigned int)__builtin_bit_cast(unsigned short, hF));
      store_short_sc(XhHi + xi,
                     (unsigned int)__builtin_bit_cast(unsigned short, hhv));
      store_short_sc(XhLo + xi,
                     (unsigned int)__builtin_bit_cast(unsigned short, hlv));
    }
    // drain write-through stores to IC before publishing arrival
    asm volatile("s_waitcnt vmcnt(0)" ::: "memory");
    __syncthreads();

    if (t < L_DIM - 1) {
      const int target = t + 1;
      if (tid == 0)
        __hip_atomic_store(&flags[wg << 4], target, __ATOMIC_RELAXED,
                           __HIP_MEMORY_SCOPE_AGENT);
      if (tid < NWG) {
        while (__hip_atomic_load(&flags[tid << 4], __ATOMIC_RELAXED,
                                 __HIP_MEMORY_SCOPE_AGENT) < target)
          __builtin_amdgcn_s_sleep(1);
      }
      __syncthreads();
    }
  }
}

// ---------------------------------------------------------------------------
// K3: split-bf16 (hi+lo) NT GEMM — ~fp32 via 3 products (FWM projections).
// MODE 1: C = acc + bias ; MODE 2: C = tanh(acc + bias)
// ---------------------------------------------------------------------------
template <int MODE>
__global__ __launch_bounds__(256) void gemm_nt3(const bf16* __restrict__ A_hi,
                                                const bf16* __restrict__ A_lo,
                                                const bf16* __restrict__ B_hi,
                                                const bf16* __restrict__ B_lo,
                                                const float* __restrict__ bias,
                                                float* __restrict__ C,
                                                int M, int N, int K)
{
  __shared__ __align__(16) bf16 As[2][128 * 32];
  __shared__ __align__(16) bf16 Bs[2][128 * 32];
  const int tid  = threadIdx.x;
  const int lane = tid & 63;
  const int w    = tid >> 6;
  const int wm   = w >> 1, wn = w & 1;
  const int m0   = blockIdx.x * 128, n0 = blockIdx.y * 128;

  f32x4_t acc[4][4];
#pragma unroll
  for (int m = 0; m < 4; ++m)
#pragma unroll
    for (int n = 0; n < 4; ++n) acc[m][n] = (f32x4_t){0.f, 0.f, 0.f, 0.f};

  for (int k0 = 0; k0 < K; k0 += 32) {
#pragma unroll
    for (int r = 0; r < 2; ++r) {
      const int base = w * 2048 + r * 1024;
      const int off  = base + lane * 16;
      const int e    = off >> 1;
      const int row  = e >> 5;
      const int col  = e & 31;
      const size_t gA = (size_t)(m0 + row) * K + (k0 + col);
      const size_t gB = (size_t)(n0 + row) * K + (k0 + col);
      gl_lds16(A_hi + gA, (char*)As[0] + base);
      gl_lds16(A_lo + gA, (char*)As[1] + base);
      gl_lds16(B_hi + gB, (char*)Bs[0] + base);
      gl_lds16(B_lo + gB, (char*)Bs[1] + base);
    }
    __syncthreads();

    bf16x8_t afh[4], afl[4], bfh[4], bfl[4];
    const int kb = (lane >> 4) * 16;
#pragma unroll
    for (int m = 0; m < 4; ++m) {
      const int ro = (wm * 64 + m * 16 + (lane & 15)) * 64 + kb;
      afh[m] = *reinterpret_cast<const bf16x8_t*>((const char*)As[0] + ro);
      afl[m] = *reinterpret_cast<const bf16x8_t*>((const char*)As[1] + ro);
    }
#pragma unroll
    for (int n = 0; n < 4; ++n) {
      const int ro = (wn * 64 + n * 16 + (lane & 15)) * 64 + kb;
      bfh[n] = *reinterpret_cast<const bf16x8_t*>((const char*)Bs[0] + ro);
      bfl[n] = *reinterpret_cast<const bf16x8_t*>((const char*)Bs[1] + ro);
    }
#pragma unroll
    for (int m = 0; m < 4; ++m)
#pragma unroll
      for (int n = 0; n < 4; ++n) {
        acc[m][n] = __builtin_amdgcn_mfma_f32_16x16x32_bf16(afh[m], bfh[n], acc[m][n], 0, 0, 0);
        acc[m][n] = __builtin_amdgcn_mfma_f32_16x16x32_bf16(afh[m], bfl[n], acc[m][n], 0, 0, 0);
        acc[m][n] = __builtin_amdgcn_mfma_f32_16x16x32_bf16(afl[m], bfh[n], acc[m][n], 0, 0, 0);
      }
    __syncthreads();
  }

#pragma unroll
  for (int m = 0; m < 4; ++m) {
#pragma unroll
    for (int n = 0; n < 4; ++n) {
      const int col = n0 + wn * 64 + n * 16 + (lane & 15);
      const float bv = bias[col];
#pragma unroll
      for (int r = 0; r < 4; ++r) {
        const int row = m0 + wm * 64 + m * 16 + (lane >> 4) * 4 + r;
        float v = acc[m][n][r] + bv;
        if (MODE == 2) v = tanhf(v);
        C[(size_t)row * N + col] = v;
      }
    }
  }
}

// ---------------------------------------------------------------------------
// K4: FWM scan. 16 WGs (one per batch) x 1024 thr. Fm register-resident.
// ---------------------------------------------------------------------------
__global__ __launch_bounds__(1024) void fwm_scan(const float* __restrict__ Wall,   // (4096,128)
                                                 const float* __restrict__ RVall,  // (4096,128)
                                                 const float* __restrict__ F0,     // (16,1024,32)
                                                 float* __restrict__ QS)           // (4096,32)
{
  const int b    = blockIdx.x;
  const int tid  = threadIdx.x;
  const int lane = tid & 63;
  const int wv   = tid >> 6;

  __shared__ float s_s[32], s_r[32], s_tv[32], s_bb;
  __shared__ float s_rv[128];
  __shared__ float s_v[32], s_u[32], s_q[32];
  __shared__ float s_red[16];
  __shared__ float s_inv;

  float F[16][2];
#pragma unroll
  for (int i = 0; i < 16; ++i)
#pragma unroll
    for (int j = 0; j < 2; ++j)
      F[i][j] = F0[((size_t)b * 1024 + (16 * lane + i)) * 32 + 2 * wv + j];

  const int si    = lane >> 1;
  const int rbase = 16 * (lane & 1);

  for (int t = 0; t < 256; ++t) {
    const float* wrow  = Wall  + (size_t)(t * 16 + b) * 128;
    const float* rvrow = RVall + (size_t)(t * 16 + b) * 128;
    __syncthreads();
    if (tid < 32)            s_s[tid]        = tanhf(wrow[tid]);
    else if (tid < 64)       s_r[tid - 32]   = tanhf(wrow[tid]);
    else if (tid < 96)       s_tv[tid - 64]  = tanhf(wrow[tid]);
    else if (tid == 96)      s_bb            = sigmoidf_(wrow[96] + 1.f);
    else if (tid >= 128 && tid < 256) s_rv[tid - 128] = rvrow[tid - 128];
    __syncthreads();

    const float sv = s_s[si];
    float sr[16];
#pragma unroll
    for (int i = 0; i < 16; ++i) sr[i] = sv * s_r[rbase + i];

    float p0 = 0.f, p1 = 0.f;
#pragma unroll
    for (int i = 0; i < 16; ++i) { p0 += sr[i] * F[i][0]; p1 += sr[i] * F[i][1]; }
#pragma unroll
    for (int m = 1; m < 64; m <<= 1) { p0 += __shfl_xor(p0, m); p1 += __shfl_xor(p1, m); }
    if (lane == 0) { s_v[2 * wv] = p0; s_v[2 * wv + 1] = p1; }
    __syncthreads();

    if (tid < 32) s_u[tid] = s_bb * (s_tv[tid] - s_v[tid]);
    __syncthreads();

    const float u0 = s_u[2 * wv], u1 = s_u[2 * wv + 1];
    float nn = 0.f;
#pragma unroll
    for (int i = 0; i < 16; ++i) {
      F[i][0] += sr[i] * u0;
      F[i][1] += sr[i] * u1;
      nn += F[i][0] * F[i][0] + F[i][1] * F[i][1];
    }
#pragma unroll
    for (int m = 1; m < 64; m <<= 1) nn += __shfl_xor(nn, m);
    if (lane == 0) s_red[wv] = nn;
    __syncthreads();
    if (tid == 0) {
      float tot = 0.f;
#pragma unroll
      for (int k = 0; k < 16; ++k) tot += s_red[k];
      const float n_ = sqrtf(tot);
      const float d  = fmaxf(n_ - 1.f, 0.f) + 1.f;
      s_inv = 1.f / d;
    }
    __syncthreads();
    const float inv = s_inv;
#pragma unroll
    for (int i = 0; i < 16; ++i) { F[i][0] *= inv; F[i][1] *= inv; }

#pragma unroll 1
    for (int jit = 0; jit < 3; ++jit) {
      const float qv = (jit == 0) ? s_rv[si] : s_q[si];
      float c0 = 0.f, c1 = 0.f;
#pragma unroll
      for (int i = 0; i < 16; ++i) {
        const float cf = qv * s_rv[32 + 32 * jit + rbase + i];
        c0 += cf * F[i][0];
        c1 += cf * F[i][1];
      }
#pragma unroll
      for (int m = 1; m < 64; m <<= 1) { c0 += __shfl_xor(c0, m); c1 += __shfl_xor(c1, m); }
      if (lane == 0) { s_v[2 * wv] = c0; s_v[2 * wv + 1] = c1; }
      __syncthreads();
      if (wv == 0 && lane < 32) {
        const float x = s_v[lane];
        float mval = x;
#pragma unroll
        for (int m = 1; m < 32; m <<= 1) mval += __shfl_xor(mval, m);
        mval *= (1.f / 32.f);
        const float dl = x - mval;
        float var = dl * dl;
#pragma unroll
        for (int m = 1; m < 32; m <<= 1) var += __shfl_xor(var, m);
        var *= (1.f / 32.f);
        s_q[lane] = dl * rsqrtf(var + 1e-5f);
      }
      __syncthreads();
    }
    if (wv == 0 && lane < 32) QS[(size_t)(t * 16 + b) * 32 + lane] = s_q[lane];
  }
}

// ---------------------------------------------------------------------------
// K5: out = (XhHi+XhLo) + QS @ Wlin^T + blin
// ---------------------------------------------------------------------------
__global__ __launch_bounds__(256) void out_kernel(const bf16* __restrict__ Xh1Hi,
                                                  const bf16* __restrict__ Xh1Lo,
                                                  const float* __restrict__ QS,
                                                  const float* __restrict__ Wlin,  // (2048,32)
                                                  const float* __restrict__ blin,
                                                  float* __restrict__ out)
{
  __shared__ float qs[32];
  const int row = blockIdx.x;
  if (threadIdx.x < 32) qs[threadIdx.x] = QS[(size_t)row * 32 + threadIdx.x];
  __syncthreads();
  for (int h = threadIdx.x; h < H_DIM; h += 256) {
    const size_t xi = (size_t)row * H_DIM + h;
    float acc = (float)Xh1Hi[xi] + (float)Xh1Lo[xi] + blin[h];
    const float* wr = Wlin + (size_t)h * 32;
#pragma unroll
    for (int t2 = 0; t2 < 32; ++t2) acc += qs[t2] * wr[t2];
    out[xi] = acc;
  }
}

// ---------------------------------------------------------------------------
// Workspace (~237 MB), lifetime-aliased:
//  Whh_f16 33.5 | Wih_f16 33.5 (XhLo aliases after Gin GEMM) |
//  inp_f16 16.8 (XhHi aliases) | Gin 134 (Wall/RVall/QS alias after persist) |
//  Xh_f16 16.9 | Wq/Wr hi/lo 2.1 | flags 16KB | smalls
// ---------------------------------------------------------------------------
extern "C" void kernel_launch(void* const* d_in, const int* in_sizes, int n_in,
                              void* d_out, int out_size, void* d_ws, size_t ws_size,
                              hipStream_t stream)
{
  (void)in_sizes; (void)n_in; (void)out_size; (void)ws_size;
  const float* inp  = (const float*)d_in[0];
  const float* h0   = (const float*)d_in[1];
  const float* c0   = (const float*)d_in[2];
  const float* F0   = (const float*)d_in[3];
  const float* Wih  = (const float*)d_in[4];
  const float* Whh  = (const float*)d_in[5];
  const float* bih  = (const float*)d_in[6];
  const float* bhh  = (const float*)d_in[7];
  const float* Www  = (const float*)d_in[8];
  const float* Wwb  = (const float*)d_in[9];
  const float* Wrw  = (const float*)d_in[10];
  const float* Wrb  = (const float*)d_in[11];
  const float* Wlin = (const float*)d_in[12];
  const float* blin = (const float*)d_in[13];
  float* out = (float*)d_out;

  char* p = (char*)d_ws;
  auto alloc = [&](size_t bytes) {
    char* r = p;
    p += (bytes + 255) & ~(size_t)255;
    return r;
  };
  _Float16* Whh_f = (_Float16*)alloc(16777216ull * 2);   // 33.5 MB
  _Float16* Wih_f = (_Float16*)alloc(16777216ull * 2);   // 33.5 MB
  _Float16* inp_f = (_Float16*)alloc(8388608ull * 2);    // 16.8 MB
  float*    Gin   = (float*)alloc(33554432ull * 4);      // 134 MB (4096x8192)
  _Float16* Xh    = (_Float16*)alloc(257ull * 32768 * 2);// 16.9 MB
  bf16*  Wq_hi  = (bf16*)alloc(262144ull * 2);
  bf16*  Wq_lo  = (bf16*)alloc(262144ull * 2);
  bf16*  Wr_hi  = (bf16*)alloc(262144ull * 2);
  bf16*  Wr_lo  = (bf16*)alloc(262144ull * 2);
  float* wbpad  = (float*)alloc(128ull * 4);
  int*   flags  = (int*)alloc(NWG * 64);                 // 64B line per WG
  // aliases (strictly later lifetimes):
  bf16*  XhHi  = (bf16*)inp_f;          // written by persist after Gin GEMM consumed inp_f
  bf16*  XhLo  = (bf16*)Wih_f;          // written after Wih consumed
  float* Wall  = Gin;                   // 2 MB, written after persist consumed Gin
  float* RVall = Gin + 524288;          // 2 MB
  float* QS    = Gin + 1048576;         // 0.5 MB

  prep_kernel<<<2048, 256, 0, stream>>>(Wih, Whh, inp, Www, Wwb, Wrw, h0,
                                        Wih_f, Whh_f, inp_f,
                                        Wq_hi, Wq_lo, Wr_hi, Wr_lo, wbpad, Xh);

  // Phase A: Gin = x @ W_ih^T + (b_ih + b_hh)   (fp16 inputs, fp32 out)
  gemm_f16<<<dim3(32, 64), 256, 0, stream>>>(inp_f, Wih_f, bih, bhh, Gin,
                                             MROWS, G4, 2048);

  // Phase B: persistent cooperative LSTM (W_hh register-resident, fp16)
  hipMemsetAsync(flags, 0, NWG * 64, stream);
  {
    void* kargs[] = {
      (void*)&Whh_f, (void*)&Gin, (void*)&bih, (void*)&bhh, (void*)&c0,
      (void*)&Xh, (void*)&XhHi, (void*)&XhLo, (void*)&flags
    };
    hipLaunchCooperativeKernel((const void*)lstm_persist, dim3(NWG), dim3(512),
                               kargs, 0, stream);
  }

  // Phase C: FWM projections (~fp32 via split-bf16)
  gemm_nt3<1><<<dim3(32, 1), 256, 0, stream>>>(XhHi, XhLo, Wq_hi, Wq_lo, wbpad,
                                               Wall, MROWS, 128, 2048);
  gemm_nt3<2><<<dim3(32, 1), 256, 0, stream>>>(XhHi, XhLo, Wr_hi, Wr_lo, Wrb,
                                               RVall, MROWS, 128, 2048);

  // Phase D: FWM scan
  fwm_scan<<<16, 1024, 0, stream>>>(Wall, RVall, F0, QS);

  // Phase E: out = x + QS @ Wlin^T + blin
  out_kernel<<<4096, 256, 0, stream>>>(XhHi, XhLo, QS, Wlin, blin, out);
}

// Round 9
// 3255.486 us; speedup vs baseline: 3.6916x; 1.1009x over previous
//
#include <hip/hip_runtime.h>
#include <hip/hip_bf16.h>
#include <cstdint>
#include <cstddef>

// Problem constants: L=256, B=16, I=2048, H=2048, S=R=T=32
#define L_DIM 256
#define B_DIM 16
#define I_DIM 2048
#define H_DIM 2048
#define G4    8192
#define MROWS 4096
#define NWG   256

typedef __hip_bfloat16 bf16;
typedef __bf16 bf16x8_t __attribute__((ext_vector_type(8)));
typedef _Float16 f16x8_t __attribute__((ext_vector_type(8)));
typedef float f32x4_t   __attribute__((ext_vector_type(4)));

__device__ __forceinline__ bf16 f2b(float f) { return __float2bfloat16(f); }

__device__ __forceinline__ void gl_lds16(const void* g, void* l) {
  __builtin_amdgcn_global_load_lds(
      (const __attribute__((address_space(1))) unsigned int*)g,
      (__attribute__((address_space(3))) unsigned int*)l, 16, 0, 0);
}

__device__ __forceinline__ float sigmoidf_(float x) { return 1.f / (1.f + expf(-x)); }

// Coherent (IC-through) access helpers — same hardware path the working
// flag protocol uses (sc1 store -> IC, sc1 load <- IC), widened to data.
__device__ __forceinline__ f16x8_t load_f16x8_sc(const _Float16* p) {
  f16x8_t r;
  asm volatile("global_load_dwordx4 %0, %1, off sc0 sc1" : "=v"(r) : "v"(p));
  return r;
}
__device__ __forceinline__ void store_short_sc(void* p, unsigned int v) {
  asm volatile("global_store_short %0, %1, off sc0 sc1" :: "v"(p), "v"(v) : "memory");
}

// ---------------------------------------------------------------------------
// K0: prep — fp16 casts (LSTM path), bf16 hi/lo (FWM weights), h0 fp16
// ---------------------------------------------------------------------------
__global__ void prep_kernel(const float* __restrict__ Wih, const float* __restrict__ Whh,
                            const float* __restrict__ inp, const float* __restrict__ Www,
                            const float* __restrict__ Wwb, const float* __restrict__ Wrw,
                            const float* __restrict__ h0,
                            _Float16* __restrict__ Wih_f, _Float16* __restrict__ Whh_f,
                            _Float16* __restrict__ inp_f,
                            bf16* __restrict__ Wq_hi, bf16* __restrict__ Wq_lo,
                            bf16* __restrict__ Wr_hi, bf16* __restrict__ Wr_lo,
                            float* __restrict__ wbpad,
                            _Float16* __restrict__ Xh0)
{
  size_t idx0 = (size_t)blockIdx.x * blockDim.x + threadIdx.x;
  size_t stride = (size_t)gridDim.x * blockDim.x;
  for (size_t i = idx0; i < 16777216ull; i += stride) {
    Wih_f[i] = (_Float16)Wih[i];
    Whh_f[i] = (_Float16)Whh[i];
  }
  for (size_t i = idx0; i < 8388608ull; i += stride) inp_f[i] = (_Float16)inp[i];
  for (size_t i = idx0; i < 262144ull; i += stride) {
    size_t r = i >> 11;
    float q = (r < 97) ? Www[i] : 0.f;
    bf16 qh = f2b(q);
    Wq_hi[i] = qh;
    Wq_lo[i] = f2b(q - (float)qh);
    float rr = Wrw[i];
    bf16 rh = f2b(rr);
    Wr_hi[i] = rh;
    Wr_lo[i] = f2b(rr - (float)rh);
  }
  for (size_t i = idx0; i < 128ull; i += stride) wbpad[i] = (i < 97) ? Wwb[i] : 0.f;
  for (size_t i = idx0; i < 32768ull; i += stride) Xh0[i] = (_Float16)h0[i];
}

// ---------------------------------------------------------------------------
// K1: fp16 NT GEMM  C(M,N) = A(M,K) * B(N,K)^T + bias[col]  (fp32 out)
// ---------------------------------------------------------------------------
__global__ __launch_bounds__(256) void gemm_f16(const _Float16* __restrict__ A,
                                                const _Float16* __restrict__ B,
                                                const float* __restrict__ bih,
                                                const float* __restrict__ bhh,
                                                float* __restrict__ C,
                                                int M, int N, int K)
{
  __shared__ __align__(16) _Float16 As[128 * 32];
  __shared__ __align__(16) _Float16 Bs[128 * 32];
  const int tid  = threadIdx.x;
  const int lane = tid & 63;
  const int w    = tid >> 6;
  const int wm   = w >> 1, wn = w & 1;
  const int m0   = blockIdx.x * 128, n0 = blockIdx.y * 128;

  f32x4_t acc[4][4];
#pragma unroll
  for (int m = 0; m < 4; ++m)
#pragma unroll
    for (int n = 0; n < 4; ++n) acc[m][n] = (f32x4_t){0.f, 0.f, 0.f, 0.f};

  for (int k0 = 0; k0 < K; k0 += 32) {
#pragma unroll
    for (int r = 0; r < 2; ++r) {
      const int base = w * 2048 + r * 1024;
      const int off  = base + lane * 16;
      const int e    = off >> 1;
      const int row  = e >> 5;
      const int col  = e & 31;
      gl_lds16(A + (size_t)(m0 + row) * K + (k0 + col), (char*)As + base);
      gl_lds16(B + (size_t)(n0 + row) * K + (k0 + col), (char*)Bs + base);
    }
    __syncthreads();

    f16x8_t af[4], bfr[4];
    const int kb = (lane >> 4) * 16;
#pragma unroll
    for (int m = 0; m < 4; ++m)
      af[m] = *reinterpret_cast<const f16x8_t*>((const char*)As + (wm * 64 + m * 16 + (lane & 15)) * 64 + kb);
#pragma unroll
    for (int n = 0; n < 4; ++n)
      bfr[n] = *reinterpret_cast<const f16x8_t*>((const char*)Bs + (wn * 64 + n * 16 + (lane & 15)) * 64 + kb);
#pragma unroll
    for (int m = 0; m < 4; ++m)
#pragma unroll
      for (int n = 0; n < 4; ++n)
        acc[m][n] = __builtin_amdgcn_mfma_f32_16x16x32_f16(af[m], bfr[n], acc[m][n], 0, 0, 0);
    __syncthreads();
  }

#pragma unroll
  for (int m = 0; m < 4; ++m) {
#pragma unroll
    for (int n = 0; n < 4; ++n) {
      const int col = n0 + wn * 64 + n * 16 + (lane & 15);
      const float bv = bih[col] + bhh[col];
#pragma unroll
      for (int r = 0; r < 4; ++r) {
        const int row = m0 + wm * 64 + m * 16 + (lane >> 4) * 4 + r;
        C[(size_t)row * N + col] = acc[m][n][r] + bv;
      }
    }
  }
}

// ---------------------------------------------------------------------------
// K2: persistent LSTM. 256 WGs x 512 thr (8 waves), cooperative.
// W_hh fp16 fragments register-resident; fence-free IC h-exchange (round 8).
// ---------------------------------------------------------------------------
__global__ __launch_bounds__(512, 2) void lstm_persist(
    const _Float16* __restrict__ Whh,
    const float* __restrict__ Gin,
    const float* __restrict__ bih, const float* __restrict__ bhh,
    const float* __restrict__ c0,
    _Float16* __restrict__ Xh,          // 257 slots (16,2048) fp16
    bf16* __restrict__ XhHi, bf16* __restrict__ XhLo,  // 256 slots
    int* flags)                          // NWG x 16 ints (64B stride)
{
  const int tid  = threadIdx.x;
  const int lane = tid & 63;
  const int wv   = tid >> 6;          // 0..7
  const int wg   = blockIdx.x;        // 0..255
  const int j0   = wg * 8;
  const int kw   = wv * 256;

  __shared__ float part[8][2][16][17];   // padded: conflict-free reduce

  // ---- register-resident W_hh fragments (B-operand layout) ----
  f16x8_t whh[2][8];
  {
    const int nn  = lane & 15;
    const int kfo = (lane >> 4) * 8;
#pragma unroll
    for (int nt = 0; nt < 2; ++nt) {
      const int n = nt * 16 + nn;
      const int gate = n >> 3, jj = n & 7;
      const size_t grow = (size_t)(gate * H_DIM + j0 + jj) * 2048;
#pragma unroll
      for (int ks = 0; ks < 8; ++ks)
        whh[nt][ks] = *reinterpret_cast<const f16x8_t*>(Whh + grow + kw + ks * 32 + kfo);
    }
  }

  // ---- per-thread cell state + bias (threads 0..127) ----
  float c_reg = 0.f, cbr0 = 0.f, cbr1 = 0.f, cbr2 = 0.f, cbr3 = 0.f;
  if (tid < 128) {
    const int bb = tid & 15, jj = tid >> 4;
    const int j = j0 + jj;
    c_reg = c0[bb * H_DIM + j];
    cbr0 = bih[0 * H_DIM + j] + bhh[0 * H_DIM + j];
    cbr1 = bih[1 * H_DIM + j] + bhh[1 * H_DIM + j];
    cbr2 = bih[2 * H_DIM + j] + bhh[2 * H_DIM + j];
    cbr3 = bih[3 * H_DIM + j] + bhh[3 * H_DIM + j];
  }

  const size_t arow = (size_t)(lane & 15) * 2048 + kw + (lane >> 4) * 8;

  for (int t = 0; t < L_DIM; ++t) {
    // Gin for this step (plain cached loads; written by a prior kernel)
    float gin0 = 0.f, gin1 = 0.f, gin2 = 0.f, gin3 = 0.f;
    if (tid < 128) {
      const int bb = tid & 15, jj = tid >> 4;
      const size_t gb = ((size_t)t * 16 + bb) * G4 + j0 + jj;
      gin0 = Gin[gb + 0 * H_DIM];
      gin1 = Gin[gb + 1 * H_DIM];
      gin2 = Gin[gb + 2 * H_DIM];
      gin3 = Gin[gb + 3 * H_DIM];
    }

    // h fragments from Xh slot t — coherent IC reads (bypass L1/L2)
    const size_t hoff = (size_t)t * 32768 + arow;
    f16x8_t hf[8];
#pragma unroll
    for (int ks = 0; ks < 8; ++ks)
      hf[ks] = load_f16x8_sc(Xh + hoff + ks * 32);
    asm volatile("s_waitcnt vmcnt(0)" ::: "memory");
    __builtin_amdgcn_sched_barrier(0);   // rule #18: keep MFMAs below the wait

    f32x4_t acc0 = {0.f, 0.f, 0.f, 0.f}, acc1 = {0.f, 0.f, 0.f, 0.f};
#pragma unroll
    for (int ks = 0; ks < 8; ++ks) {
      acc0 = __builtin_amdgcn_mfma_f32_16x16x32_f16(hf[ks], whh[0][ks], acc0, 0, 0, 0);
      acc1 = __builtin_amdgcn_mfma_f32_16x16x32_f16(hf[ks], whh[1][ks], acc1, 0, 0, 0);
    }
#pragma unroll
    for (int r = 0; r < 4; ++r) {
      part[wv][0][(lane >> 4) * 4 + r][lane & 15] = acc0[r];
      part[wv][1][(lane >> 4) * 4 + r][lane & 15] = acc1[r];
    }
    __syncthreads();

    if (tid < 128) {
      const int bb = tid & 15, jj = tid >> 4;
      float g[4] = {gin0, gin1, gin2, gin3};
      const float cb4[4] = {cbr0, cbr1, cbr2, cbr3};
#pragma unroll
      for (int gate = 0; gate < 4; ++gate) {
        const int n = gate * 8 + jj;
        const int ntile = n >> 4, nc = n & 15;
        float s = 0.f;
#pragma unroll
        for (int v = 0; v < 8; ++v) s += part[v][ntile][bb][nc];
        g[gate] += s + cb4[gate];
      }
      const float i_ = sigmoidf_(g[0]);
      const float f_ = sigmoidf_(g[1]);
      const float g_ = tanhf(g[2]);
      const float o_ = sigmoidf_(g[3]);
      c_reg = f_ * c_reg + i_ * g_;
      const float h = o_ * tanhf(c_reg);
      const int bj = bb * 2048 + j0 + jj;
      // write-through (IC) stores: fp16 for recurrence, bf16 hi/lo for FWM
      const _Float16 hF = (_Float16)h;
      const bf16 hhv = f2b(h);
      const bf16 hlv = f2b(h - (float)hhv);
      const size_t xi = ((size_t)t * 16 + bb) * 2048 + j0 + jj;
      store_short_sc(Xh + (size_t)(t + 1) * 32768 + bj,
                     (unsigned int)__builtin_bit_cast(unsigned short, hF));
      store_short_sc(XhHi + xi,
                     (unsigned int)__builtin_bit_cast(unsigned short, hhv));
      store_short_sc(XhLo + xi,
                     (unsigned int)__builtin_bit_cast(unsigned short, hlv));
    }
    // drain write-through stores to IC before publishing arrival
    asm volatile("s_waitcnt vmcnt(0)" ::: "memory");
    __syncthreads();

    if (t < L_DIM - 1) {
      const int target = t + 1;
      if (tid == 0)
        __hip_atomic_store(&flags[wg << 4], target, __ATOMIC_RELAXED,
                           __HIP_MEMORY_SCOPE_AGENT);
      if (tid < NWG) {
        while (__hip_atomic_load(&flags[tid << 4], __ATOMIC_RELAXED,
                                 __HIP_MEMORY_SCOPE_AGENT) < target)
          __builtin_amdgcn_s_sleep(1);
      }
      __syncthreads();
    }
  }
}

// ---------------------------------------------------------------------------
// K3: split-bf16 (hi+lo) NT GEMM — ~fp32 via 3 products (FWM projections).
// MODE 1: C = acc + bias ; MODE 2: C = tanh(acc + bias)
// ---------------------------------------------------------------------------
template <int MODE>
__global__ __launch_bounds__(256) void gemm_nt3(const bf16* __restrict__ A_hi,
                                                const bf16* __restrict__ A_lo,
                                                const bf16* __restrict__ B_hi,
                                                const bf16* __restrict__ B_lo,
                                                const float* __restrict__ bias,
                                                float* __restrict__ C,
                                                int M, int N, int K)
{
  __shared__ __align__(16) bf16 As[2][128 * 32];
  __shared__ __align__(16) bf16 Bs[2][128 * 32];
  const int tid  = threadIdx.x;
  const int lane = tid & 63;
  const int w    = tid >> 6;
  const int wm   = w >> 1, wn = w & 1;
  const int m0   = blockIdx.x * 128, n0 = blockIdx.y * 128;

  f32x4_t acc[4][4];
#pragma unroll
  for (int m = 0; m < 4; ++m)
#pragma unroll
    for (int n = 0; n < 4; ++n) acc[m][n] = (f32x4_t){0.f, 0.f, 0.f, 0.f};

  for (int k0 = 0; k0 < K; k0 += 32) {
#pragma unroll
    for (int r = 0; r < 2; ++r) {
      const int base = w * 2048 + r * 1024;
      const int off  = base + lane * 16;
      const int e    = off >> 1;
      const int row  = e >> 5;
      const int col  = e & 31;
      const size_t gA = (size_t)(m0 + row) * K + (k0 + col);
      const size_t gB = (size_t)(n0 + row) * K + (k0 + col);
      gl_lds16(A_hi + gA, (char*)As[0] + base);
      gl_lds16(A_lo + gA, (char*)As[1] + base);
      gl_lds16(B_hi + gB, (char*)Bs[0] + base);
      gl_lds16(B_lo + gB, (char*)Bs[1] + base);
    }
    __syncthreads();

    bf16x8_t afh[4], afl[4], bfh[4], bfl[4];
    const int kb = (lane >> 4) * 16;
#pragma unroll
    for (int m = 0; m < 4; ++m) {
      const int ro = (wm * 64 + m * 16 + (lane & 15)) * 64 + kb;
      afh[m] = *reinterpret_cast<const bf16x8_t*>((const char*)As[0] + ro);
      afl[m] = *reinterpret_cast<const bf16x8_t*>((const char*)As[1] + ro);
    }
#pragma unroll
    for (int n = 0; n < 4; ++n) {
      const int ro = (wn * 64 + n * 16 + (lane & 15)) * 64 + kb;
      bfh[n] = *reinterpret_cast<const bf16x8_t*>((const char*)Bs[0] + ro);
      bfl[n] = *reinterpret_cast<const bf16x8_t*>((const char*)Bs[1] + ro);
    }
#pragma unroll
    for (int m = 0; m < 4; ++m)
#pragma unroll
      for (int n = 0; n < 4; ++n) {
        acc[m][n] = __builtin_amdgcn_mfma_f32_16x16x32_bf16(afh[m], bfh[n], acc[m][n], 0, 0, 0);
        acc[m][n] = __builtin_amdgcn_mfma_f32_16x16x32_bf16(afh[m], bfl[n], acc[m][n], 0, 0, 0);
        acc[m][n] = __builtin_amdgcn_mfma_f32_16x16x32_bf16(afl[m], bfh[n], acc[m][n], 0, 0, 0);
      }
    __syncthreads();
  }

#pragma unroll
  for (int m = 0; m < 4; ++m) {
#pragma unroll
    for (int n = 0; n < 4; ++n) {
      const int col = n0 + wn * 64 + n * 16 + (lane & 15);
      const float bv = bias[col];
#pragma unroll
      for (int r = 0; r < 4; ++r) {
        const int row = m0 + wm * 64 + m * 16 + (lane >> 4) * 4 + r;
        float v = acc[m][n][r] + bv;
        if (MODE == 2) v = tanhf(v);
        C[(size_t)row * N + col] = v;
      }
    }
  }
}

// ---------------------------------------------------------------------------
// K4: FWM scan — restructured. 16 WGs x 512 thr (8 waves).
// Wave wv owns t-cols [4wv,4wv+4); lane owns k in [16*lane,+16).
// Serial q-chain factored via G_jit[i,t] = sum_j rj_j F[32i+j,t] (q-free,
// computed in parallel); norm tracked incrementally (no 32K reduce).
// 5 syncthreads/step.
// ---------------------------------------------------------------------------
__global__ __launch_bounds__(512, 2) void fwm_scan(const float* __restrict__ Wall,   // (4096,128)
                                                   const float* __restrict__ RVall,  // (4096,128)
                                                   const float* __restrict__ F0,     // (16,1024,32)
                                                   float* __restrict__ QS)           // (4096,32)
{
  const int b    = blockIdx.x;
  const int tid  = threadIdx.x;
  const int lane = tid & 63;
  const int wv   = tid >> 6;          // 0..7

  __shared__ float s_s[32], s_r[32], s_tv[32], s_bb;
  __shared__ float s_rv[128];
  __shared__ float s_v[32], s_u[32], s_q[32];
  __shared__ float s_inv;
  __shared__ float s_red[8];
  __shared__ float s_G[3][32][33];    // padded cols: conflict-free

  const int si    = lane >> 1;        // s-index for this lane's k-range
  const int rbase = 16 * (lane & 1);  // r-index base

  float F[16][4];
#pragma unroll
  for (int i = 0; i < 16; ++i)
#pragma unroll
    for (int j = 0; j < 4; ++j)
      F[i][j] = F0[((size_t)b * 1024 + (16 * lane + i)) * 32 + 4 * wv + j];

  // initial ||F||^2 (one-time full reduce)
  float N = 0.f;
  {
    float loc = 0.f;
#pragma unroll
    for (int i = 0; i < 16; ++i)
#pragma unroll
      for (int j = 0; j < 4; ++j) loc += F[i][j] * F[i][j];
#pragma unroll
    for (int m = 1; m < 64; m <<= 1) loc += __shfl_xor(loc, m);
    if (lane == 0) s_red[wv] = loc;
    __syncthreads();
#pragma unroll
    for (int k = 0; k < 8; ++k) N += s_red[k];
  }

  for (int t = 0; t < 256; ++t) {
    const float* wrow  = Wall  + (size_t)(t * 16 + b) * 128;
    const float* rvrow = RVall + (size_t)(t * 16 + b) * 128;
    // prefetch staging values (plain loads; read-only sources)
    float wpre = 0.f, rvpre = 0.f;
    if (tid < 97) wpre = wrow[tid];
    if (tid >= 128 && tid < 256) rvpre = rvrow[tid - 128];
    __syncthreads();                  // A: prior step's readers done
    if (tid < 32)       s_s[tid]       = tanhf(wpre);
    else if (tid < 64)  s_r[tid - 32]  = tanhf(wpre);
    else if (tid < 96)  s_tv[tid - 64] = tanhf(wpre);
    else if (tid == 96) s_bb           = sigmoidf_(wpre + 1.f);
    else if (tid >= 128 && tid < 256) s_rv[tid - 128] = rvpre;
    __syncthreads();                  // B

    const float sv = s_s[si];
    float sr[16];
#pragma unroll
    for (int i = 0; i < 16; ++i) sr[i] = sv * s_r[rbase + i];

    // v_t = sum_k sr[k] F[k,t] (wave-local t-columns)
    float vv4[4];
#pragma unroll
    for (int j = 0; j < 4; ++j) {
      float pp = 0.f;
#pragma unroll
      for (int i = 0; i < 16; ++i) pp += sr[i] * F[i][j];
#pragma unroll
      for (int m = 1; m < 64; m <<= 1) pp += __shfl_xor(pp, m);
      vv4[j] = pp;
    }
    if (lane == 0) {
#pragma unroll
      for (int j = 0; j < 4; ++j) s_v[4 * wv + j] = vv4[j];
    }
    __syncthreads();                  // C

    // wave 0: u, incremental norm, inv
    if (wv == 0) {
      const float vt  = (lane < 32) ? s_v[lane]  : 0.f;
      const float tvt = (lane < 32) ? s_tv[lane] : 0.f;
      const float ut  = (lane < 32) ? s_bb * (tvt - vt) : 0.f;
      if (lane < 32) s_u[lane] = ut;
      const float sl = (lane < 32) ? s_s[lane] : 0.f;
      const float rl = (lane < 32) ? s_r[lane] : 0.f;
      float uv = ut * vt, uu = ut * ut, ss = sl * sl, rr = rl * rl;
#pragma unroll
      for (int m = 1; m < 64; m <<= 1) {
        uv += __shfl_xor(uv, m);
        uu += __shfl_xor(uu, m);
        ss += __shfl_xor(ss, m);
        rr += __shfl_xor(rr, m);
      }
      const float Np  = N + 2.f * uv + ss * rr * uu;
      const float n_  = sqrtf(Np);
      const float inv = 1.f / (fmaxf(n_ - 1.f, 0.f) + 1.f);
      N = Np * inv * inv;
      if (lane == 0) s_inv = inv;
    }
    __syncthreads();                  // D

    // F update + scale (elementwise), then parallel G matrices
    const float inv = s_inv;
    float uw[4];
#pragma unroll
    for (int j = 0; j < 4; ++j) uw[j] = s_u[4 * wv + j];
#pragma unroll
    for (int i = 0; i < 16; ++i)
#pragma unroll
      for (int j = 0; j < 4; ++j)
        F[i][j] = (F[i][j] + sr[i] * uw[j]) * inv;

#pragma unroll
    for (int jit = 0; jit < 3; ++jit) {
      float rjv[16];
#pragma unroll
      for (int i = 0; i < 16; ++i) rjv[i] = s_rv[32 + 32 * jit + rbase + i];
#pragma unroll
      for (int j = 0; j < 4; ++j) {
        float g = 0.f;
#pragma unroll
        for (int i = 0; i < 16; ++i) g += rjv[i] * F[i][j];
        g += __shfl_xor(g, 1);        // combine the two j-halves of row i
        if ((lane & 1) == 0) s_G[jit][lane >> 1][4 * wv + j] = g;
      }
    }
    __syncthreads();                  // E

    // wave 0: short serial q-chain (3 x 32x32 matvec + LN) + QS store
    if (wv == 0 && lane < 32) {
      float q = s_rv[lane];
#pragma unroll 1
      for (int jit = 0; jit < 3; ++jit) {
        s_q[lane] = q;
        float c = 0.f;
#pragma unroll
        for (int i = 0; i < 32; ++i) c += s_q[i] * s_G[jit][i][lane];
        float mval = c;
#pragma unroll
        for (int m = 1; m < 32; m <<= 1) mval += __shfl_xor(mval, m);
        mval *= (1.f / 32.f);
        const float dl = c - mval;
        float var = dl * dl;
#pragma unroll
        for (int m = 1; m < 32; m <<= 1) var += __shfl_xor(var, m);
        var *= (1.f / 32.f);
        q = dl * rsqrtf(var + 1e-5f);
      }
      QS[(size_t)(t * 16 + b) * 32 + lane] = q;
    }
  }
}

// ---------------------------------------------------------------------------
// K5: out = (XhHi+XhLo) + QS @ Wlin^T + blin
// ---------------------------------------------------------------------------
__global__ __launch_bounds__(256) void out_kernel(const bf16* __restrict__ Xh1Hi,
                                                  const bf16* __restrict__ Xh1Lo,
                                                  const float* __restrict__ QS,
                                                  const float* __restrict__ Wlin,  // (2048,32)
                                                  const float* __restrict__ blin,
                                                  float* __restrict__ out)
{
  __shared__ float qs[32];
  const int row = blockIdx.x;
  if (threadIdx.x < 32) qs[threadIdx.x] = QS[(size_t)row * 32 + threadIdx.x];
  __syncthreads();
  for (int h = threadIdx.x; h < H_DIM; h += 256) {
    const size_t xi = (size_t)row * H_DIM + h;
    float acc = (float)Xh1Hi[xi] + (float)Xh1Lo[xi] + blin[h];
    const float* wr = Wlin + (size_t)h * 32;
#pragma unroll
    for (int t2 = 0; t2 < 32; ++t2) acc += qs[t2] * wr[t2];
    out[xi] = acc;
  }
}

// ---------------------------------------------------------------------------
// Workspace (~237 MB), lifetime-aliased:
//  Whh_f16 33.5 | Wih_f16 33.5 (XhLo aliases after Gin GEMM) |
//  inp_f16 16.8 (XhHi aliases) | Gin 134 (Wall/RVall/QS alias after persist) |
//  Xh_f16 16.9 | Wq/Wr hi/lo 2.1 | flags 16KB | smalls
// ---------------------------------------------------------------------------
extern "C" void kernel_launch(void* const* d_in, const int* in_sizes, int n_in,
                              void* d_out, int out_size, void* d_ws, size_t ws_size,
                              hipStream_t stream)
{
  (void)in_sizes; (void)n_in; (void)out_size; (void)ws_size;
  const float* inp  = (const float*)d_in[0];
  const float* h0   = (const float*)d_in[1];
  const float* c0   = (const float*)d_in[2];
  const float* F0   = (const float*)d_in[3];
  const float* Wih  = (const float*)d_in[4];
  const float* Whh  = (const float*)d_in[5];
  const float* bih  = (const float*)d_in[6];
  const float* bhh  = (const float*)d_in[7];
  const float* Www  = (const float*)d_in[8];
  const float* Wwb  = (const float*)d_in[9];
  const float* Wrw  = (const float*)d_in[10];
  const float* Wrb  = (const float*)d_in[11];
  const float* Wlin = (const float*)d_in[12];
  const float* blin = (const float*)d_in[13];
  float* out = (float*)d_out;

  char* p = (char*)d_ws;
  auto alloc = [&](size_t bytes) {
    char* r = p;
    p += (bytes + 255) & ~(size_t)255;
    return r;
  };
  _Float16* Whh_f = (_Float16*)alloc(16777216ull * 2);   // 33.5 MB
  _Float16* Wih_f = (_Float16*)alloc(16777216ull * 2);   // 33.5 MB
  _Float16* inp_f = (_Float16*)alloc(8388608ull * 2);    // 16.8 MB
  float*    Gin   = (float*)alloc(33554432ull * 4);      // 134 MB (4096x8192)
  _Float16* Xh    = (_Float16*)alloc(257ull * 32768 * 2);// 16.9 MB
  bf16*  Wq_hi  = (bf16*)alloc(262144ull * 2);
  bf16*  Wq_lo  = (bf16*)alloc(262144ull * 2);
  bf16*  Wr_hi  = (bf16*)alloc(262144ull * 2);
  bf16*  Wr_lo  = (bf16*)alloc(262144ull * 2);
  float* wbpad  = (float*)alloc(128ull * 4);
  int*   flags  = (int*)alloc(NWG * 64);                 // 64B line per WG
  // aliases (strictly later lifetimes):
  bf16*  XhHi  = (bf16*)inp_f;          // written by persist after Gin GEMM consumed inp_f
  bf16*  XhLo  = (bf16*)Wih_f;          // written after Wih consumed
  float* Wall  = Gin;                   // 2 MB, written after persist consumed Gin
  float* RVall = Gin + 524288;          // 2 MB
  float* QS    = Gin + 1048576;         // 0.5 MB

  prep_kernel<<<2048, 256, 0, stream>>>(Wih, Whh, inp, Www, Wwb, Wrw, h0,
                                        Wih_f, Whh_f, inp_f,
                                        Wq_hi, Wq_lo, Wr_hi, Wr_lo, wbpad, Xh);

  // Phase A: Gin = x @ W_ih^T + (b_ih + b_hh)   (fp16 inputs, fp32 out)
  gemm_f16<<<dim3(32, 64), 256, 0, stream>>>(inp_f, Wih_f, bih, bhh, Gin,
                                             MROWS, G4, 2048);

  // Phase B: persistent cooperative LSTM (W_hh register-resident, fp16)
  hipMemsetAsync(flags, 0, NWG * 64, stream);
  {
    void* kargs[] = {
      (void*)&Whh_f, (void*)&Gin, (void*)&bih, (void*)&bhh, (void*)&c0,
      (void*)&Xh, (void*)&XhHi, (void*)&XhLo, (void*)&flags
    };
    hipLaunchCooperativeKernel((const void*)lstm_persist, dim3(NWG), dim3(512),
                               kargs, 0, stream);
  }

  // Phase C: FWM projections (~fp32 via split-bf16)
  gemm_nt3<1><<<dim3(32, 1), 256, 0, stream>>>(XhHi, XhLo, Wq_hi, Wq_lo, wbpad,
                                               Wall, MROWS, 128, 2048);
  gemm_nt3<2><<<dim3(32, 1), 256, 0, stream>>>(XhHi, XhLo, Wr_hi, Wr_lo, Wrb,
                                               RVall, MROWS, 128, 2048);

  // Phase D: FWM scan (restructured: parallel G, incremental norm)
  fwm_scan<<<16, 512, 0, stream>>>(Wall, RVall, F0, QS);

  // Phase E: out = x + QS @ Wlin^T + blin
  out_kernel<<<4096, 256, 0, stream>>>(XhHi, XhLo, QS, Wlin, blin, out);
}